// Round 8
// baseline (696.138 us; speedup 1.0000x reference)
//
#include <hip/hip_runtime.h>
#include <math.h>

// Problem constants (B=4096, T=100, F=13, H=100)
#define B_    4096
#define T_    100
#define F_    13
#define H_    100

typedef int   i32x4 __attribute__((ext_vector_type(4)));
typedef float f32x4 __attribute__((ext_vector_type(4)));

// ---- ws layout (bytes), total 364,544 ----
#define O_HIST   0u        // 512
#define O_ROWMAP 512u      // 4096*4
#define O_BIAS0  16896u    // 448*4
#define O_BIAS1  18688u    // 448*4
#define O_B0     20480u    // L0 i8 frags: 2kt*4g*7ct*2pl*1024 = 114688
#define O_B1     135168u   // L1 i8 frags: 4kt*4g*7ct*2pl*1024 = 229376 -> 364544

// ---- int16 quantization scheme (v8, unchanged in v9) ----
// A (state) int16 as two i8 planes (hi*256+lo), uniform scale 1/32768 of the
// pre-scaled value: h stored as h/2 (rint(h*16384)); x as x/8 (rint(x*4096)).
// The /2,/8 are folded into weights (2x/8x rows) at prep.
// B (weights) int16 = rint(w_eff*SB), i8 hi/lo planes.
// z = bias + K1*(Ahi.Bhi) + K2*(Ahi.Blo + Alo.Bhi)   [Alo.Blo dropped ~1e-5]
#define SB0_F  40000.0f
#define SB1_F  160000.0f
#define K1_0   ((float)(65536.0 / (32768.0 * 40000.0)))
#define K2_0   ((float)(256.0   / (32768.0 * 40000.0)))
#define K1_1   ((float)(65536.0 / (32768.0 * 160000.0)))
#define K2_1   ((float)(256.0   / (32768.0 * 160000.0)))

// B-fragment array layout (bytes), per layer:
//   idx = ((((kt*4 + g)*7 + ct)*2 + plane)*64 + lane)*16 + j    (plane0=hi)
// lane's frag byte j holds W_plane[k = kt*64 + (lane>>4)*16 + j]
//                          [col = g*112 + ct*16 + (lane&15)]

__device__ __forceinline__ float sigmoid_f(float v) {
    return 1.0f / (1.0f + __expf(-v));
}
__device__ __forceinline__ float tanh_f(float v) {
    float e = __expf(2.0f * v);
    return 1.0f - 2.0f / (e + 1.0f);
}
// quantize a pre-scaled value to int16 and split into i8 hi/lo (hi*256+lo = a)
__device__ __forceinline__ void qsplit(float v_scaled, signed char& hi, signed char& lo) {
    int a = (int)rintf(v_scaled);
    a = a > 32639 ? 32639 : (a < -32640 ? -32640 : a);
    int l = ((a + 128) & 255) - 128;   // l in [-128,127], a-l divisible by 256
    hi = (signed char)((a - l) >> 8);
    lo = (signed char)l;
}

// async global->LDS, 16 B per lane. LDS dest = wave-uniform base + lane*16;
// global src is per-lane. (v6-validated address-space casts.)
__device__ __forceinline__ void gload16(const void* g, void* l) {
    __builtin_amdgcn_global_load_lds(
        (const __attribute__((address_space(1))) void*)(unsigned long long)g,
        (__attribute__((address_space(3))) void*)(unsigned)(unsigned long long)l,
        16, 0, 0);
}
// inline-asm LDS read (invisible to compiler waitcnt tracking; paired with
// explicit lgkmcnt(0)+sched_barrier per rule #18)
__device__ __forceinline__ i32x4 dsr128(unsigned a) {
    i32x4 r;
    asm volatile("ds_read_b128 %0, %1" : "=v"(r) : "v"(a));
    return r;
}
// barrier that publishes LDS (lgkmcnt) but does NOT drain vmcnt: the in-flight
// global_load_lds staging is per-wave-private, so cross-wave correctness only
// needs LDS writes committed. This keeps the B-prefetch pipeline alive across
// barriers (the m97-structure vmcnt(0) drain was the stall).
#define BAR_LGKM() do {                                        \
    asm volatile("s_waitcnt lgkmcnt(0)" ::: "memory");         \
    __builtin_amdgcn_sched_barrier(0);                         \
    __builtin_amdgcn_s_barrier();                              \
    __builtin_amdgcn_sched_barrier(0);                         \
} while (0)

// ---------------- prep: counting sort of rows by length ----------------
__global__ void k_hist(const int* __restrict__ len, int* __restrict__ hist) {
    int b = blockIdx.x * blockDim.x + threadIdx.x;
    if (b < B_) atomicAdd(&hist[len[b]], 1);
}
__global__ void k_scan(int* __restrict__ hist) {
    if (threadIdx.x == 0 && blockIdx.x == 0) {
        int acc = 0;
        for (int l = 0; l <= 100; ++l) { int c = hist[l]; hist[l] = acc; acc += c; }
    }
}
__global__ void k_scatter(const int* __restrict__ len, int* __restrict__ hist,
                          int* __restrict__ rowmap) {
    int b = blockIdx.x * blockDim.x + threadIdx.x;
    if (b < B_) {
        int pos = atomicAdd(&hist[len[b]], 1);
        rowmap[pos] = b;
    }
}

// ---------------- prep: biases (gate-major, padded) ----------------
__global__ void k_prep_bias(const float* __restrict__ bih0, const float* __restrict__ bhh0,
                            const float* __restrict__ bih1, const float* __restrict__ bhh1,
                            float* __restrict__ bias0, float* __restrict__ bias1) {
    int idx = blockIdx.x * blockDim.x + threadIdx.x;
    if (idx < 448) {
        int g = idx / 112, cell = idx % 112;
        float v0 = 0.f, v1 = 0.f;
        if (cell < 100) {
            int row = g * 100 + cell;
            v0 = bih0[row] + bhh0[row];
            v1 = bih1[row] + bhh1[row];
        }
        bias0[idx] = v0; bias1[idx] = v1;
    }
}

// ---------------- prep: weights -> int16 -> i8 hi/lo fragment planes -------
__global__ void k_prep_b_i8(const float* __restrict__ Wih0, const float* __restrict__ Whh0,
                            const float* __restrict__ Wih1, const float* __restrict__ Whh1,
                            signed char* __restrict__ B0, signed char* __restrict__ B1) {
    int idx = blockIdx.x * blockDim.x + threadIdx.x;
    if (idx >= 344064) return;                 // 114688 + 229376
    const bool isL0 = (idx < 114688);
    int t = isL0 ? idx : idx - 114688;
    int fr    = t >> 11;                       // (kt*4+g)*7 + ct
    int rem   = t & 2047;
    int plane = rem >> 10;
    int e     = rem & 1023;
    int lane = e >> 4, j = e & 15;
    int i = fr / 7, ct = fr % 7;
    int kt = i >> 2, g = i & 3;
    int n = lane & 15, q = lane >> 4;
    int k = kt * 64 + q * 16 + j;
    int cell = ct * 16 + n;

    float w = 0.f;
    if (cell < 100) {
        int row = g * 100 + cell;
        if (isL0) {
            if (k < 100)      w = 2.0f * Whh0[row * 100 + k];
            else if (k < 113) w = 8.0f * Wih0[row * 13 + (k - 100)];
        } else {
            if (k < 100)      w = 2.0f * Wih1[row * 100 + k];
            else if (k < 200) w = 2.0f * Whh1[row * 100 + (k - 100)];
        }
    }
    int a = (int)rintf(w * (isL0 ? SB0_F : SB1_F));
    a = a > 32639 ? 32639 : (a < -32640 ? -32640 : a);
    int l = ((a + 128) & 255) - 128;
    signed char byte = plane ? (signed char)l : (signed char)((a - l) >> 8);
    if (isL0) B0[idx] = byte; else B1[t] = byte;
}

// ---------------- main persistent MFMA LSTM ----------------
// v9: v8 numerics (bit-identical; absmax canary 0.0002441406) + deep B
// pipeline:
//  * B staged L2->LDS via global_load_lds into per-wave double-buffered 8 KB
//    kt-pairs (8 frags: bhi/blo x 4g); consumed via asm ds_read_b128.
//  * Counted s_waitcnt vmcnt(8): at each kt, pair j+1 stays in flight; pair
//    j+2 issued right after pair j's ds_reads complete. NEVER drains.
//  * In-loop barriers = raw s_barrier + lgkmcnt(0) only (no vmcnt drain) ->
//    the prefetch pipeline survives phase/step boundaries; the pair consumed
//    right after each barrier had the whole pointwise+barrier to land.
//    Safe: all cross-wave data (A-state h/x) is LDS (lgkm); staging is
//    per-wave private.
//  * Pair schedule/step (6 pairs): P1kt0(b0),P1kt1(b1) | P2kt0(b0)..P2kt3(b1);
//    issue at pair j: j+2 -> {P1kt0->P2kt0, P1kt1->P2kt1, P2kt0->P2kt2,
//    P2kt1->P2kt3, P2kt2->next P1kt0, P2kt3->next P1kt1}. Prologue issues
//    pairs 0,1 after the last full __syncthreads.
//  * LDS: A-state ~26 KB + staging 7*16 KB = ~141.4 KB (< 160 KiB).
// Waves 0..6: cell-tile ct, all 4 gates. Wave 7: x loader.
__global__ __attribute__((amdgpu_flat_work_group_size(512, 512), amdgpu_waves_per_eu(2, 2)))
void k_lstm(
    const float* __restrict__ x, const int* __restrict__ lengths,
    const int* __restrict__ rowmap,
    const signed char* __restrict__ B0, const signed char* __restrict__ B1,
    const float* __restrict__ bias0, const float* __restrict__ bias1,
    const float* __restrict__ Wfc, const float* __restrict__ bfc,
    float* __restrict__ out)
{
    __shared__ __align__(16) signed char Ah0[2][16 * 144];
    __shared__ __align__(16) signed char Al0[2][16 * 144];
    __shared__ __align__(16) signed char Ah1[2][16 * 272];
    __shared__ __align__(16) signed char Al1[2][16 * 272];
    __shared__ __align__(16) signed char Bst[7][2][8192];   // per-wave dbuf pairs
    __shared__ int sRow[16], sLen[16], sTmax;

    const int tid = threadIdx.x;
    const int wv = tid >> 6, lane = tid & 63;

    if (tid < 16) {
        int r = rowmap[blockIdx.x * 16 + tid];
        sRow[tid] = r; sLen[tid] = lengths[r];
    }
    for (int i = tid; i < 16 * 144; i += 512) {
        Ah0[0][i] = 0; Al0[0][i] = 0; Ah0[1][i] = 0; Al0[1][i] = 0;
    }
    for (int i = tid; i < 16 * 272; i += 512) {
        Ah1[0][i] = 0; Al1[0][i] = 0; Ah1[1][i] = 0; Al1[1][i] = 0;
    }
    __syncthreads();   // (pre-1) sRow/sLen + zero-init published
    if (tid == 0) { int m = 0; for (int i = 0; i < 16; ++i) m = max(m, sLen[i]); sTmax = m; }

    // ---- per-wave setup ----
    const int ct = (wv < 7) ? wv : 0, n = lane & 15, q = lane >> 4;
    const int cell = ct * 16 + n;

    float b0v[4], b1v[4];
    int   lenR[4];
    float c0[4], c1[4];
    int offA0, offA1;
    const signed char* B0w = B0 + ct * 2048 + lane * 16;
    const signed char* B1w = B1 + ct * 2048 + lane * 16;
    const unsigned bstBase = (wv < 7)
        ? (unsigned)(unsigned long long)(const void*)&Bst[wv][0][lane * 16] : 0u;
    if (wv < 7) {
#pragma unroll
        for (int g = 0; g < 4; ++g) {
            b0v[g] = bias0[g * 112 + cell];
            b1v[g] = bias1[g * 112 + cell];
        }
        offA0 = n * 144 + q * 16;
        offA1 = n * 272 + q * 16;
#pragma unroll
        for (int r = 0; r < 4; ++r) {
            lenR[r] = sLen[q * 4 + r];       // C row = q*4 + r
            c0[r] = 0.f; c1[r] = 0.f;
        }
    }

    // wave 7: x loader (16 rows x 13 feats = 208 slots, 4 per lane)
    int xvalid[4]; size_t xg[4]; int xa[4]; float xv[4];
    if (wv == 7) {
#pragma unroll
        for (int i = 0; i < 4; ++i) {
            int e = i * 64 + lane;
            xvalid[i] = (e < 208);
            int r = xvalid[i] ? (e / 13) : 0;
            int f = xvalid[i] ? (e - 13 * r) : 0;
            xg[i] = (size_t)sRow[r] * (T_ * F_) + f;
            xa[i] = r * 144 + 100 + f;
            xv[i] = xvalid[i] ? x[xg[i]] : 0.f;   // t = 0
        }
    }
    __syncthreads();   // (pre-2) sTmax published
    const int Tmax = sTmax;
    if (wv == 7) {     // write x_0 into buffer 0 (x/8 repr: rint(x*4096))
#pragma unroll
        for (int i = 0; i < 4; ++i) if (xvalid[i]) {
            signed char hi, lo; qsplit(xv[i] * 4096.0f, hi, lo);
            Ah0[0][xa[i]] = hi; Al0[0][xa[i]] = lo;
        }
    }
    __syncthreads();   // (pre-3) x_0 published; full drain (vmcnt empty here)

    // prologue: issue pairs 0,1 (L0 kt0 -> buf0, L0 kt1 -> buf1)
    if (wv < 7) {
#pragma unroll
        for (int g = 0; g < 4; ++g) {
            gload16(B0w + (size_t)(0 * 4 + g) * 14336,        &Bst[wv][0][g * 1024]);
            gload16(B0w + (size_t)(0 * 4 + g) * 14336 + 1024, &Bst[wv][0][4096 + g * 1024]);
        }
#pragma unroll
        for (int g = 0; g < 4; ++g) {
            gload16(B0w + (size_t)(1 * 4 + g) * 14336,        &Bst[wv][1][g * 1024]);
            gload16(B0w + (size_t)(1 * 4 + g) * 14336 + 1024, &Bst[wv][1][4096 + g * 1024]);
        }
    }

    for (int t = 0; t < Tmax; ++t) {
        const int p = t & 1, pn = p ^ 1;
        // =============== phase 1: layer-0 (reads A0[p], K=128) ===============
        if (wv < 7) {
            i32x4 HH[4], MM[4];
#pragma unroll
            for (int g = 0; g < 4; ++g) {
                HH[g] = (i32x4){0, 0, 0, 0};
                MM[g] = (i32x4){0, 0, 0, 0};
            }
#pragma unroll
            for (int kt = 0; kt < 2; ++kt) {       // pair parity: buf = kt
                asm volatile("s_waitcnt vmcnt(8)" ::: "memory");
                __builtin_amdgcn_sched_barrier(0);
                const unsigned bb = bstBase + kt * 8192;
                i32x4 bh0 = dsr128(bb);
                i32x4 bh1 = dsr128(bb + 1024);
                i32x4 bh2 = dsr128(bb + 2048);
                i32x4 bh3 = dsr128(bb + 3072);
                i32x4 bl0 = dsr128(bb + 4096);
                i32x4 bl1 = dsr128(bb + 5120);
                i32x4 bl2 = dsr128(bb + 6144);
                i32x4 bl3 = dsr128(bb + 7168);
                i32x4 ahi = *(const i32x4*)&Ah0[p][offA0 + kt * 64];
                i32x4 alo = *(const i32x4*)&Al0[p][offA0 + kt * 64];
                asm volatile("s_waitcnt lgkmcnt(0)" ::: "memory");
                __builtin_amdgcn_sched_barrier(0);
                // issue pair j+2: L1 kt{0,1} -> same (just-freed) buf
#pragma unroll
                for (int g = 0; g < 4; ++g) {
                    gload16(B1w + (size_t)(kt * 4 + g) * 14336,        &Bst[wv][kt][g * 1024]);
                    gload16(B1w + (size_t)(kt * 4 + g) * 14336 + 1024, &Bst[wv][kt][4096 + g * 1024]);
                }
                HH[0] = __builtin_amdgcn_mfma_i32_16x16x64_i8(ahi, bh0, HH[0], 0, 0, 0);
                MM[0] = __builtin_amdgcn_mfma_i32_16x16x64_i8(ahi, bl0, MM[0], 0, 0, 0);
                MM[0] = __builtin_amdgcn_mfma_i32_16x16x64_i8(alo, bh0, MM[0], 0, 0, 0);
                HH[1] = __builtin_amdgcn_mfma_i32_16x16x64_i8(ahi, bh1, HH[1], 0, 0, 0);
                MM[1] = __builtin_amdgcn_mfma_i32_16x16x64_i8(ahi, bl1, MM[1], 0, 0, 0);
                MM[1] = __builtin_amdgcn_mfma_i32_16x16x64_i8(alo, bh1, MM[1], 0, 0, 0);
                HH[2] = __builtin_amdgcn_mfma_i32_16x16x64_i8(ahi, bh2, HH[2], 0, 0, 0);
                MM[2] = __builtin_amdgcn_mfma_i32_16x16x64_i8(ahi, bl2, MM[2], 0, 0, 0);
                MM[2] = __builtin_amdgcn_mfma_i32_16x16x64_i8(alo, bh2, MM[2], 0, 0, 0);
                HH[3] = __builtin_amdgcn_mfma_i32_16x16x64_i8(ahi, bh3, HH[3], 0, 0, 0);
                MM[3] = __builtin_amdgcn_mfma_i32_16x16x64_i8(ahi, bl3, MM[3], 0, 0, 0);
                MM[3] = __builtin_amdgcn_mfma_i32_16x16x64_i8(alo, bh3, MM[3], 0, 0, 0);
            }
            // pointwise + state update
            float hreg[4];
#pragma unroll
            for (int r = 0; r < 4; ++r) {
                float zi = b0v[0] + K1_0 * (float)HH[0][r] + K2_0 * (float)MM[0][r];
                float zf = b0v[1] + K1_0 * (float)HH[1][r] + K2_0 * (float)MM[1][r];
                float zg = b0v[2] + K1_0 * (float)HH[2][r] + K2_0 * (float)MM[2][r];
                float zo = b0v[3] + K1_0 * (float)HH[3][r] + K2_0 * (float)MM[3][r];
                float cn = sigmoid_f(zf) * c0[r] + sigmoid_f(zi) * tanh_f(zg);
                float hn = sigmoid_f(zo) * tanh_f(cn);
                if (t < lenR[r]) c0[r] = cn;
                hreg[r] = hn;
            }
            // h0n -> A0[pn] (GEMM0 at t+1) and A1[p] (GEMM1 this step)
            if (cell < 100) {
#pragma unroll
                for (int r = 0; r < 4; ++r) {
                    if (t < lenR[r]) {
                        int m = q * 4 + r;
                        signed char hi, lo; qsplit(hreg[r] * 16384.0f, hi, lo);
                        Ah0[pn][m * 144 + cell] = hi; Al0[pn][m * 144 + cell] = lo;
                        Ah1[p][m * 272 + cell]  = hi; Al1[p][m * 272 + cell]  = lo;
                    }
                }
            }
        } else if (wv == 7) {
            // wave 7: load x(t+1) and write into A0[pn] (read next at t+1)
            if (t + 1 < Tmax) {
#pragma unroll
                for (int i = 0; i < 4; ++i)
                    if (xvalid[i]) xv[i] = x[xg[i] + (size_t)(t + 1) * F_];
#pragma unroll
                for (int i = 0; i < 4; ++i) if (xvalid[i]) {
                    signed char hi, lo; qsplit(xv[i] * 4096.0f, hi, lo);
                    Ah0[pn][xa[i]] = hi; Al0[pn][xa[i]] = lo;
                }
            }
        }
        BAR_LGKM();        // (A) h0n published in A1[p]; staging stays in flight
        // =============== phase 2: layer-1 (reads A1[p], K=256) ===============
        if (wv < 7) {
            i32x4 HH[4], MM[4];
#pragma unroll
            for (int g = 0; g < 4; ++g) {
                HH[g] = (i32x4){0, 0, 0, 0};
                MM[g] = (i32x4){0, 0, 0, 0};
            }
#pragma unroll
            for (int kt = 0; kt < 4; ++kt) {       // pair buf = kt & 1
                asm volatile("s_waitcnt vmcnt(8)" ::: "memory");
                __builtin_amdgcn_sched_barrier(0);
                const unsigned bb = bstBase + (kt & 1) * 8192;
                i32x4 bh0 = dsr128(bb);
                i32x4 bh1 = dsr128(bb + 1024);
                i32x4 bh2 = dsr128(bb + 2048);
                i32x4 bh3 = dsr128(bb + 3072);
                i32x4 bl0 = dsr128(bb + 4096);
                i32x4 bl1 = dsr128(bb + 5120);
                i32x4 bl2 = dsr128(bb + 6144);
                i32x4 bl3 = dsr128(bb + 7168);
                i32x4 ahi = *(const i32x4*)&Ah1[p][offA1 + kt * 64];
                i32x4 alo = *(const i32x4*)&Al1[p][offA1 + kt * 64];
                asm volatile("s_waitcnt lgkmcnt(0)" ::: "memory");
                __builtin_amdgcn_sched_barrier(0);
                // issue pair j+2: kt0->L1kt2, kt1->L1kt3, kt2->next L0kt0,
                // kt3->next L0kt1 (dead-but-harmless at final t)
                if (kt < 2) {
#pragma unroll
                    for (int g = 0; g < 4; ++g) {
                        gload16(B1w + (size_t)((kt + 2) * 4 + g) * 14336,        &Bst[wv][kt & 1][g * 1024]);
                        gload16(B1w + (size_t)((kt + 2) * 4 + g) * 14336 + 1024, &Bst[wv][kt & 1][4096 + g * 1024]);
                    }
                } else {
#pragma unroll
                    for (int g = 0; g < 4; ++g) {
                        gload16(B0w + (size_t)((kt - 2) * 4 + g) * 14336,        &Bst[wv][kt & 1][g * 1024]);
                        gload16(B0w + (size_t)((kt - 2) * 4 + g) * 14336 + 1024, &Bst[wv][kt & 1][4096 + g * 1024]);
                    }
                }
                HH[0] = __builtin_amdgcn_mfma_i32_16x16x64_i8(ahi, bh0, HH[0], 0, 0, 0);
                MM[0] = __builtin_amdgcn_mfma_i32_16x16x64_i8(ahi, bl0, MM[0], 0, 0, 0);
                MM[0] = __builtin_amdgcn_mfma_i32_16x16x64_i8(alo, bh0, MM[0], 0, 0, 0);
                HH[1] = __builtin_amdgcn_mfma_i32_16x16x64_i8(ahi, bh1, HH[1], 0, 0, 0);
                MM[1] = __builtin_amdgcn_mfma_i32_16x16x64_i8(ahi, bl1, MM[1], 0, 0, 0);
                MM[1] = __builtin_amdgcn_mfma_i32_16x16x64_i8(alo, bh1, MM[1], 0, 0, 0);
                HH[2] = __builtin_amdgcn_mfma_i32_16x16x64_i8(ahi, bh2, HH[2], 0, 0, 0);
                MM[2] = __builtin_amdgcn_mfma_i32_16x16x64_i8(ahi, bl2, MM[2], 0, 0, 0);
                MM[2] = __builtin_amdgcn_mfma_i32_16x16x64_i8(alo, bh2, MM[2], 0, 0, 0);
                HH[3] = __builtin_amdgcn_mfma_i32_16x16x64_i8(ahi, bh3, HH[3], 0, 0, 0);
                MM[3] = __builtin_amdgcn_mfma_i32_16x16x64_i8(ahi, bl3, MM[3], 0, 0, 0);
                MM[3] = __builtin_amdgcn_mfma_i32_16x16x64_i8(alo, bh3, MM[3], 0, 0, 0);
            }
            float hreg[4];
#pragma unroll
            for (int r = 0; r < 4; ++r) {
                float zi = b1v[0] + K1_1 * (float)HH[0][r] + K2_1 * (float)MM[0][r];
                float zf = b1v[1] + K1_1 * (float)HH[1][r] + K2_1 * (float)MM[1][r];
                float zg = b1v[2] + K1_1 * (float)HH[2][r] + K2_1 * (float)MM[2][r];
                float zo = b1v[3] + K1_1 * (float)HH[3][r] + K2_1 * (float)MM[3][r];
                float cn = sigmoid_f(zf) * c1[r] + sigmoid_f(zi) * tanh_f(zg);
                float hn = sigmoid_f(zo) * tanh_f(cn);
                if (t < lenR[r]) c1[r] = cn;
                hreg[r] = hn;
            }
            // h1n -> A1[pn] (read at t+1); frozen rows keep value in buf (len&1)
            if (cell < 100) {
#pragma unroll
                for (int r = 0; r < 4; ++r) {
                    if (t < lenR[r]) {
                        int m = q * 4 + r;
                        signed char hi, lo; qsplit(hreg[r] * 16384.0f, hi, lo);
                        Ah1[pn][m * 272 + 100 + cell] = hi;
                        Al1[pn][m * 272 + 100 + cell] = lo;
                    }
                }
            }
        }
        BAR_LGKM();        // (B) A0[pn] (h0n+x) and A1[pn] (h1n) published
    }
    __syncthreads();       // full drain (also retires dead tail prefetches)

    // final: out[b] = W_fc . h1 + b_fc; h1 stored as int16 repr of h/2 in
    // buffer len&1 (last write at t=len-1 targeted parity (len-1)^1 = len&1)
    if (tid < 16) {
        const int par = sLen[tid] & 1;
        float s = bfc[0];
        for (int j = 0; j < 100; ++j) {
            int a = ((int)Ah1[par][tid * 272 + 100 + j]) * 256 +
                    (int)Al1[par][tid * 272 + 100 + j];
            float h = (float)a * (1.0f / 16384.0f);
            s = fmaf(Wfc[j], h, s);
        }
        out[sRow[tid]] = s;
    }
}

// ---------------- launch ----------------
extern "C" void kernel_launch(void* const* d_in, const int* in_sizes, int n_in,
                              void* d_out, int out_size, void* d_ws, size_t ws_size,
                              hipStream_t stream) {
    const float* x    = (const float*)d_in[0];
    const int*   len  = (const int*)d_in[1];
    const float* Wih0 = (const float*)d_in[2];
    const float* Whh0 = (const float*)d_in[3];
    const float* bih0 = (const float*)d_in[4];
    const float* bhh0 = (const float*)d_in[5];
    const float* Wih1 = (const float*)d_in[6];
    const float* Whh1 = (const float*)d_in[7];
    const float* bih1 = (const float*)d_in[8];
    const float* bhh1 = (const float*)d_in[9];
    const float* Wfc  = (const float*)d_in[10];
    const float* bfc  = (const float*)d_in[11];
    float* out = (float*)d_out;

    char* ws = (char*)d_ws;   // uses 364,544 bytes
    int*         hist   = (int*)(ws + O_HIST);
    int*         rowmap = (int*)(ws + O_ROWMAP);
    float*       bias0  = (float*)(ws + O_BIAS0);
    float*       bias1  = (float*)(ws + O_BIAS1);
    signed char* B0     = (signed char*)(ws + O_B0);
    signed char* B1     = (signed char*)(ws + O_B1);

    hipMemsetAsync(hist, 0, 512, stream);
    k_hist<<<16, 256, 0, stream>>>(len, hist);
    k_scan<<<1, 64, 0, stream>>>(hist);
    k_scatter<<<16, 256, 0, stream>>>(len, hist, rowmap);
    k_prep_bias<<<2, 256, 0, stream>>>(bih0, bhh0, bih1, bhh1, bias0, bias1);
    k_prep_b_i8<<<1344, 256, 0, stream>>>(Wih0, Whh0, Wih1, Whh1, B0, B1);
    k_lstm<<<256, 512, 0, stream>>>(x, len, rowmap, B0, B1, bias0, bias1, Wfc, bfc, out);
}

// Round 9
// 611.526 us; speedup vs baseline: 1.1384x; 1.1384x over previous
//
#include <hip/hip_runtime.h>
#include <math.h>

// Problem constants (B=4096, T=100, F=13, H=100)
#define B_    4096
#define T_    100
#define F_    13
#define H_    100

typedef int   i32x4 __attribute__((ext_vector_type(4)));
typedef float f32x4 __attribute__((ext_vector_type(4)));

// ---- ws layout (bytes), total 249,856 ----
#define O_HIST   0u        // 512
#define O_ROWMAP 512u      // 4096*4
#define O_BIAS0  16896u    // 448*4
#define O_BIAS1  18688u    // 448*4
#define O_B0     20480u    // L0 int16-as-2xi8: 2kt*4g*7ct*2pl*1024 = 114688
#define O_B1     135168u   // L1 int8 single plane: 4kt*4g*7ct*1024 = 114688 -> 249856

// ---- quantization scheme (v10) ----
// State (A): int16 as two i8 planes (hi*256+lo), scale 1/32768 of stored val:
//   h stored as h/2 (a = rint(h*16384), no clamp since |h|<1)
//   x stored as x/8 (a = rint(x*4096), |x|<8 effectively always)
// L0 weights (B0): int16 = rint(w_eff*40000), i8 hi/lo planes (v8 scheme):
//   w_eff = 2*Whh0 (h cols, <=0.2) or 8*Wih0 (x cols, <=0.8)
//   z0 = bias + K1_0*(Ahi.Bhi) + K2_0*(Ahi.Blo + Alo.Bhi)  [Alo.Blo dropped]
// L1 weights (B1): *** int8 SINGLE plane *** w_int = rint(w*1270) (|w|<0.1 ->
//   +-127 exact fit), LDS-RESIDENT (loaded once; zero steady-state stream).
//   z1 = bias + K1L1*(Ahi.B) + K2L1*(Alo.B)
//   K1L1 = 256/(1270*16384), K2L1 = 1/(1270*16384)
#define SB0_F  40000.0f
#define K1_0   ((float)(65536.0 / (32768.0 * 40000.0)))
#define K2_0   ((float)(256.0   / (32768.0 * 40000.0)))
#define K1L1   ((float)(256.0 / (1270.0 * 16384.0)))
#define K2L1   ((float)(1.0   / (1270.0 * 16384.0)))

// B0 fragment layout (bytes): idx = ((((kt*4+g)*7+ct)*2+plane)*64+lane)*16+j
// B1 fragment layout (bytes): idx = (((kt*4+g)*7+ct)*64+lane)*16+j
// lane's frag byte j holds W[k = kt*64 + (lane>>4)*16 + j]
//                          [col = g*112 + ct*16 + (lane&15)]

__device__ __forceinline__ float sigmoid_f(float v) {
    return 1.0f / (1.0f + __expf(-v));
}
__device__ __forceinline__ float tanh_f(float v) {
    float e = __expf(2.0f * v);
    return 1.0f - 2.0f / (e + 1.0f);
}
// quantize a pre-scaled value to int16 and split into i8 hi/lo (hi*256+lo = a)
__device__ __forceinline__ void qsplit(float v_scaled, signed char& hi, signed char& lo) {
    int a = (int)rintf(v_scaled);
    a = a > 32639 ? 32639 : (a < -32640 ? -32640 : a);
    int l = ((a + 128) & 255) - 128;   // l in [-128,127], a-l divisible by 256
    hi = (signed char)((a - l) >> 8);
    lo = (signed char)l;
}

// async global->LDS, 16 B per lane. LDS dest = wave-uniform base + lane*16;
// global src is per-lane. (v6/v9-validated.)
__device__ __forceinline__ void gload16(const void* g, void* l) {
    __builtin_amdgcn_global_load_lds(
        (const __attribute__((address_space(1))) void*)(unsigned long long)g,
        (__attribute__((address_space(3))) void*)(unsigned)(unsigned long long)l,
        16, 0, 0);
}

// ---------------- prep: counting sort of rows by length ----------------
__global__ void k_hist(const int* __restrict__ len, int* __restrict__ hist) {
    int b = blockIdx.x * blockDim.x + threadIdx.x;
    if (b < B_) atomicAdd(&hist[len[b]], 1);
}
__global__ void k_scan(int* __restrict__ hist) {
    if (threadIdx.x == 0 && blockIdx.x == 0) {
        int acc = 0;
        for (int l = 0; l <= 100; ++l) { int c = hist[l]; hist[l] = acc; acc += c; }
    }
}
__global__ void k_scatter(const int* __restrict__ len, int* __restrict__ hist,
                          int* __restrict__ rowmap) {
    int b = blockIdx.x * blockDim.x + threadIdx.x;
    if (b < B_) {
        int pos = atomicAdd(&hist[len[b]], 1);
        rowmap[pos] = b;
    }
}

// ---------------- prep: biases (gate-major, padded) ----------------
__global__ void k_prep_bias(const float* __restrict__ bih0, const float* __restrict__ bhh0,
                            const float* __restrict__ bih1, const float* __restrict__ bhh1,
                            float* __restrict__ bias0, float* __restrict__ bias1) {
    int idx = blockIdx.x * blockDim.x + threadIdx.x;
    if (idx < 448) {
        int g = idx / 112, cell = idx % 112;
        float v0 = 0.f, v1 = 0.f;
        if (cell < 100) {
            int row = g * 100 + cell;
            v0 = bih0[row] + bhh0[row];
            v1 = bih1[row] + bhh1[row];
        }
        bias0[idx] = v0; bias1[idx] = v1;
    }
}

// ---------------- prep: weights -> fragment planes ----------------
// L0 (idx < 114688): v8 int16 2-plane scheme.
//   A-k: k<100 -> h0/2 (2*Whh0), 100..112 -> x/8 (8*Wih0), >=113 -> 0
// L1 (idx >= 114688): int8 single plane, w_int = rint(w*1270).
//   A-k: k<100 -> h0n/2 (Wih1), 100..199 -> h1/2 (Whh1), >=200 -> 0
__global__ void k_prep_b_i8(const float* __restrict__ Wih0, const float* __restrict__ Whh0,
                            const float* __restrict__ Wih1, const float* __restrict__ Whh1,
                            signed char* __restrict__ B0, signed char* __restrict__ B1) {
    int idx = blockIdx.x * blockDim.x + threadIdx.x;
    if (idx >= 229376) return;                 // 114688 (L0) + 114688 (L1)
    if (idx < 114688) {                        // ---- layer 0 (unchanged v8) ----
        int t = idx;
        int fr    = t >> 11;                   // (kt*4+g)*7 + ct
        int rem   = t & 2047;
        int plane = rem >> 10;
        int e     = rem & 1023;
        int lane = e >> 4, j = e & 15;
        int i = fr / 7, ct = fr % 7;
        int kt = i >> 2, g = i & 3;
        int k = kt * 64 + (lane >> 4) * 16 + j;
        int cell = ct * 16 + (lane & 15);
        float w = 0.f;
        if (cell < 100) {
            int row = g * 100 + cell;
            if (k < 100)      w = 2.0f * Whh0[row * 100 + k];
            else if (k < 113) w = 8.0f * Wih0[row * 13 + (k - 100)];
        }
        int a = (int)rintf(w * SB0_F);
        a = a > 32639 ? 32639 : (a < -32640 ? -32640 : a);
        int l = ((a + 128) & 255) - 128;
        B0[idx] = plane ? (signed char)l : (signed char)((a - l) >> 8);
    } else {                                   // ---- layer 1 (int8 single) ----
        int t = idx - 114688;
        int fr = t >> 10;                      // (kt*4+g)*7 + ct
        int e  = t & 1023;
        int lane = e >> 4, j = e & 15;
        int i = fr / 7, ct = fr % 7;
        int kt = i >> 2, g = i & 3;
        int k = kt * 64 + (lane >> 4) * 16 + j;
        int cell = ct * 16 + (lane & 15);
        float w = 0.f;
        if (cell < 100) {
            int row = g * 100 + cell;
            if (k < 100)      w = Wih1[row * 100 + k];
            else if (k < 200) w = Whh1[row * 100 + (k - 100)];
        }
        int a = (int)rintf(w * 1270.0f);
        a = a > 127 ? 127 : (a < -127 ? -127 : a);
        B1[t] = (signed char)a;
    }
}

// ---------------- main persistent MFMA LSTM ----------------
// v10: v8 structure (256 blocks x 16 rows x 512 thr, 2 barriers/step) with:
//  * L1 weights int8 single-plane, LDS-RESIDENT (112 KB loaded once in the
//    prologue via global_load_lds) -> steady-state B stream drops 344 KB ->
//    112 KB/block-step (L0 only). v4==v6 and v8==v9 proved bytes, not
//    latency, bind (~31 B/cyc marginal); this is the next byte cut.
//  * L1 GEMM: 2 MFMAs/(kt,g): HH=Ahi.B, MM=Alo.B; z1 = bias + K1L1*HH +
//    K2L1*MM. State precision unchanged (int16); only L1 weight quant
//    coarsens (dw<=3.9e-4) -> absmax expected ~4-7e-4.
//  * L0 path byte-for-byte v8 (int16 2-plane streamed, 3 MFMAs, x in kt1).
//  * LDS: A 26.6 KB + Bres 112 KB = ~141.5 KB (v9 precedent: 141.8 KB ok).
// Waves 0..6: cell-tile ct, all 4 gates. Wave 7: x loader.
__global__ __attribute__((amdgpu_flat_work_group_size(512, 512), amdgpu_waves_per_eu(2, 2)))
void k_lstm(
    const float* __restrict__ x, const int* __restrict__ lengths,
    const int* __restrict__ rowmap,
    const signed char* __restrict__ B0, const signed char* __restrict__ B1,
    const float* __restrict__ bias0, const float* __restrict__ bias1,
    const float* __restrict__ Wfc, const float* __restrict__ bfc,
    float* __restrict__ out)
{
    // row strides 144/272 B (16-mult for aligned b128 frag reads, non-pow2 to
    // spread banks; 2-way class conflicts only)
    __shared__ __align__(16) signed char Ah0[2][16 * 144];
    __shared__ __align__(16) signed char Al0[2][16 * 144];
    __shared__ __align__(16) signed char Ah1[2][16 * 272];
    __shared__ __align__(16) signed char Al1[2][16 * 272];
    __shared__ __align__(16) signed char Bres[7][16 * 1024];  // resident L1
    __shared__ int sRow[16], sLen[16], sTmax;

    const int tid = threadIdx.x;
    const int wv = tid >> 6, lane = tid & 63;

    if (tid < 16) {
        int r = rowmap[blockIdx.x * 16 + tid];
        sRow[tid] = r; sLen[tid] = lengths[r];
    }
    for (int i = tid; i < 16 * 144; i += 512) {
        Ah0[0][i] = 0; Al0[0][i] = 0; Ah0[1][i] = 0; Al0[1][i] = 0;
    }
    for (int i = tid; i < 16 * 272; i += 512) {
        Ah1[0][i] = 0; Al1[0][i] = 0; Ah1[1][i] = 0; Al1[1][i] = 0;
    }

    // ---- per-wave setup ----
    const int ct = (wv < 7) ? wv : 0, n = lane & 15, q = lane >> 4;
    const int cell = ct * 16 + n;
    const signed char* B0w = B0 + ct * 2048 + lane * 16;
    const signed char* B1w = B1 + ct * 1024 + lane * 16;

    // prologue: stage resident L1 slice (16 frags x 1 KB per wave). Issued
    // before the barriers; __syncthreads below drains vmcnt -> data ready.
    if (wv < 7) {
#pragma unroll
        for (int fr = 0; fr < 16; ++fr)
            gload16(B1w + (size_t)fr * 7168, &Bres[wv][fr * 1024]);
    }
    __syncthreads();   // (pre-1) sRow/sLen + zero-init published
    if (tid == 0) { int m = 0; for (int i = 0; i < 16; ++i) m = max(m, sLen[i]); sTmax = m; }

    float b0v[4], b1v[4];
    int   lenR[4];
    float c0[4], c1[4];
    int offA0, offA1;
    if (wv < 7) {
#pragma unroll
        for (int g = 0; g < 4; ++g) {
            b0v[g] = bias0[g * 112 + cell];
            b1v[g] = bias1[g * 112 + cell];
        }
        offA0 = n * 144 + q * 16;
        offA1 = n * 272 + q * 16;
#pragma unroll
        for (int r = 0; r < 4; ++r) {
            lenR[r] = sLen[q * 4 + r];       // C row = q*4 + r
            c0[r] = 0.f; c1[r] = 0.f;
        }
    }

    // wave 7: x loader (16 rows x 13 feats = 208 slots, 4 per lane)
    int xvalid[4]; size_t xg[4]; int xa[4]; float xv[4];
    if (wv == 7) {
#pragma unroll
        for (int i = 0; i < 4; ++i) {
            int e = i * 64 + lane;
            xvalid[i] = (e < 208);
            int r = xvalid[i] ? (e / 13) : 0;
            int f = xvalid[i] ? (e - 13 * r) : 0;
            xg[i] = (size_t)sRow[r] * (T_ * F_) + f;
            xa[i] = r * 144 + 100 + f;
            xv[i] = xvalid[i] ? x[xg[i]] : 0.f;   // t = 0
        }
    }
    __syncthreads();   // (pre-2) sTmax published
    const int Tmax = sTmax;
    if (wv == 7) {     // write x_0 into buffer 0 (x/8 repr: rint(x*4096))
#pragma unroll
        for (int i = 0; i < 4; ++i) if (xvalid[i]) {
            signed char hi, lo; qsplit(xv[i] * 4096.0f, hi, lo);
            Ah0[0][xa[i]] = hi; Al0[0][xa[i]] = lo;
        }
    }
    __syncthreads();   // (pre-3) x_0 + resident L1 published (vmcnt drained)

    for (int t = 0; t < Tmax; ++t) {
        const int p = t & 1, pn = p ^ 1;
        // =============== phase 1: layer-0 (reads A0[p], K=128) ===============
        if (wv < 7) {
            i32x4 HH[4], MM[4];
#pragma unroll
            for (int g = 0; g < 4; ++g) {
                HH[g] = (i32x4){0, 0, 0, 0};
                MM[g] = (i32x4){0, 0, 0, 0};
            }
            i32x4 bhi[2], blo[2], ahi, alo;
            bhi[0] = *(const i32x4*)(B0w);
            blo[0] = *(const i32x4*)(B0w + 1024);
#pragma unroll
            for (int i = 0; i < 8; ++i) {     // i = kt*4 + g, kt<2
                const int kt = i >> 2, g = i & 3, cb = i & 1, nbf = cb ^ 1;
                if (i + 1 < 8) {
                    bhi[nbf] = *(const i32x4*)(B0w + (size_t)(i + 1) * 14336);
                    blo[nbf] = *(const i32x4*)(B0w + (size_t)(i + 1) * 14336 + 1024);
                }
                if (g == 0) {
                    ahi = *(const i32x4*)&Ah0[p][offA0 + kt * 64];
                    alo = *(const i32x4*)&Al0[p][offA0 + kt * 64];
                }
                HH[g] = __builtin_amdgcn_mfma_i32_16x16x64_i8(ahi, bhi[cb], HH[g], 0, 0, 0);
                MM[g] = __builtin_amdgcn_mfma_i32_16x16x64_i8(ahi, blo[cb], MM[g], 0, 0, 0);
                MM[g] = __builtin_amdgcn_mfma_i32_16x16x64_i8(alo, bhi[cb], MM[g], 0, 0, 0);
            }
            // pointwise + state update
            float hreg[4];
#pragma unroll
            for (int r = 0; r < 4; ++r) {
                float zi = b0v[0] + K1_0 * (float)HH[0][r] + K2_0 * (float)MM[0][r];
                float zf = b0v[1] + K1_0 * (float)HH[1][r] + K2_0 * (float)MM[1][r];
                float zg = b0v[2] + K1_0 * (float)HH[2][r] + K2_0 * (float)MM[2][r];
                float zo = b0v[3] + K1_0 * (float)HH[3][r] + K2_0 * (float)MM[3][r];
                float cn = sigmoid_f(zf) * c0[r] + sigmoid_f(zi) * tanh_f(zg);
                float hn = sigmoid_f(zo) * tanh_f(cn);
                if (t < lenR[r]) c0[r] = cn;
                hreg[r] = hn;
            }
            // h0n -> A0[pn] (GEMM0 at t+1) and A1[p] (GEMM1 this step)
            if (cell < 100) {
#pragma unroll
                for (int r = 0; r < 4; ++r) {
                    if (t < lenR[r]) {
                        int m = q * 4 + r;
                        signed char hi, lo; qsplit(hreg[r] * 16384.0f, hi, lo);
                        Ah0[pn][m * 144 + cell] = hi; Al0[pn][m * 144 + cell] = lo;
                        Ah1[p][m * 272 + cell]  = hi; Al1[p][m * 272 + cell]  = lo;
                    }
                }
            }
        } else {
            // wave 7: load x(t+1) and write into A0[pn] (read next at t+1)
            if (t + 1 < Tmax) {
#pragma unroll
                for (int i = 0; i < 4; ++i)
                    if (xvalid[i]) xv[i] = x[xg[i] + (size_t)(t + 1) * F_];
#pragma unroll
                for (int i = 0; i < 4; ++i) if (xvalid[i]) {
                    signed char hi, lo; qsplit(xv[i] * 4096.0f, hi, lo);
                    Ah0[pn][xa[i]] = hi; Al0[pn][xa[i]] = lo;
                }
            }
        }
        __syncthreads();   // (A) h0n published in A1[p]
        // ========== phase 2: layer-1 (reads A1[p], K=256, resident B) ========
        if (wv < 7) {
            i32x4 HH[4], MM[4];
#pragma unroll
            for (int g = 0; g < 4; ++g) {
                HH[g] = (i32x4){0, 0, 0, 0};
                MM[g] = (i32x4){0, 0, 0, 0};
            }
#pragma unroll
            for (int kt = 0; kt < 4; ++kt) {
                i32x4 ahi = *(const i32x4*)&Ah1[p][offA1 + kt * 64];
                i32x4 alo = *(const i32x4*)&Al1[p][offA1 + kt * 64];
#pragma unroll
                for (int g = 0; g < 4; ++g) {
                    i32x4 b = *(const i32x4*)&Bres[wv][(kt * 4 + g) * 1024 + lane * 16];
                    HH[g] = __builtin_amdgcn_mfma_i32_16x16x64_i8(ahi, b, HH[g], 0, 0, 0);
                    MM[g] = __builtin_amdgcn_mfma_i32_16x16x64_i8(alo, b, MM[g], 0, 0, 0);
                }
            }
            float hreg[4];
#pragma unroll
            for (int r = 0; r < 4; ++r) {
                float zi = b1v[0] + K1L1 * (float)HH[0][r] + K2L1 * (float)MM[0][r];
                float zf = b1v[1] + K1L1 * (float)HH[1][r] + K2L1 * (float)MM[1][r];
                float zg = b1v[2] + K1L1 * (float)HH[2][r] + K2L1 * (float)MM[2][r];
                float zo = b1v[3] + K1L1 * (float)HH[3][r] + K2L1 * (float)MM[3][r];
                float cn = sigmoid_f(zf) * c1[r] + sigmoid_f(zi) * tanh_f(zg);
                float hn = sigmoid_f(zo) * tanh_f(cn);
                if (t < lenR[r]) c1[r] = cn;
                hreg[r] = hn;
            }
            // h1n -> A1[pn] (read at t+1); frozen rows keep value in buf (len&1)
            if (cell < 100) {
#pragma unroll
                for (int r = 0; r < 4; ++r) {
                    if (t < lenR[r]) {
                        int m = q * 4 + r;
                        signed char hi, lo; qsplit(hreg[r] * 16384.0f, hi, lo);
                        Ah1[pn][m * 272 + 100 + cell] = hi;
                        Al1[pn][m * 272 + 100 + cell] = lo;
                    }
                }
            }
        }
        __syncthreads();   // (B) A0[pn] (h0n+x) and A1[pn] (h1n) published
    }

    // final: out[b] = W_fc . h1 + b_fc; h1 stored as int16 repr of h/2 in
    // buffer len&1 (last write at t=len-1 targeted parity (len-1)^1 = len&1)
    if (tid < 16) {
        const int par = sLen[tid] & 1;
        float s = bfc[0];
        for (int j = 0; j < 100; ++j) {
            int a = ((int)Ah1[par][tid * 272 + 100 + j]) * 256 +
                    (int)Al1[par][tid * 272 + 100 + j];
            float h = (float)a * (1.0f / 16384.0f);
            s = fmaf(Wfc[j], h, s);
        }
        out[sRow[tid]] = s;
    }
}

// ---------------- launch ----------------
extern "C" void kernel_launch(void* const* d_in, const int* in_sizes, int n_in,
                              void* d_out, int out_size, void* d_ws, size_t ws_size,
                              hipStream_t stream) {
    const float* x    = (const float*)d_in[0];
    const int*   len  = (const int*)d_in[1];
    const float* Wih0 = (const float*)d_in[2];
    const float* Whh0 = (const float*)d_in[3];
    const float* bih0 = (const float*)d_in[4];
    const float* bhh0 = (const float*)d_in[5];
    const float* Wih1 = (const float*)d_in[6];
    const float* Whh1 = (const float*)d_in[7];
    const float* bih1 = (const float*)d_in[8];
    const float* bhh1 = (const float*)d_in[9];
    const float* Wfc  = (const float*)d_in[10];
    const float* bfc  = (const float*)d_in[11];
    float* out = (float*)d_out;

    char* ws = (char*)d_ws;   // uses 249,856 bytes
    int*         hist   = (int*)(ws + O_HIST);
    int*         rowmap = (int*)(ws + O_ROWMAP);
    float*       bias0  = (float*)(ws + O_BIAS0);
    float*       bias1  = (float*)(ws + O_BIAS1);
    signed char* B0     = (signed char*)(ws + O_B0);
    signed char* B1     = (signed char*)(ws + O_B1);

    hipMemsetAsync(hist, 0, 512, stream);
    k_hist<<<16, 256, 0, stream>>>(len, hist);
    k_scan<<<1, 64, 0, stream>>>(hist);
    k_scatter<<<16, 256, 0, stream>>>(len, hist, rowmap);
    k_prep_bias<<<2, 256, 0, stream>>>(bih0, bhh0, bih1, bhh1, bias0, bias1);
    k_prep_b_i8<<<896, 256, 0, stream>>>(Wih0, Whh0, Wih1, Whh1, B0, B1);
    k_lstm<<<256, 512, 0, stream>>>(x, len, rowmap, B0, B1, bias0, bias1, Wfc, bfc, out);
}

// Round 10
// 602.103 us; speedup vs baseline: 1.1562x; 1.0156x over previous
//
#include <hip/hip_runtime.h>
#include <math.h>

// Problem constants (B=4096, T=100, F=13, H=100)
#define B_    4096
#define T_    100
#define F_    13
#define H_    100

typedef int   i32x4 __attribute__((ext_vector_type(4)));
typedef float f32x4 __attribute__((ext_vector_type(4)));

// ---- ws layout (bytes), total 249,856 ----
#define O_HIST   0u        // 512
#define O_ROWMAP 512u      // 4096*4
#define O_BIAS0  16896u    // 448*4
#define O_BIAS1  18688u    // 448*4
#define O_B0     20480u    // L0 int16-as-2xi8: 2kt*4g*7ct*2pl*1024 = 114688
#define O_B1     135168u   // L1 int8 single plane: 4kt*4g*7ct*1024 = 114688 -> 249856

// ---- quantization scheme (v10, unchanged in v11) ----
// State (A): int16 as two i8 planes (hi*256+lo), scale 1/32768 of stored val:
//   h stored as h/2 (a = rint(h*16384)); x stored as x/8 (a = rint(x*4096)).
// L0 weights (B0): int16 = rint(w_eff*40000), i8 hi/lo planes:
//   w_eff = 2*Whh0 (h cols) or 8*Wih0 (x cols)
//   z0 = bias + K1_0*(Ahi.Bhi) + K2_0*(Ahi.Blo + Alo.Bhi)  [Alo.Blo dropped]
// L1 weights (B1): int8 single plane w_int = rint(w*1270), LDS-resident.
//   z1 = bias + K1L1*(Ahi.B) + K2L1*(Alo.B)
#define SB0_F  40000.0f
#define K1_0   ((float)(65536.0 / (32768.0 * 40000.0)))
#define K2_0   ((float)(256.0   / (32768.0 * 40000.0)))
#define K1L1   ((float)(256.0 / (1270.0 * 16384.0)))
#define K2L1   ((float)(1.0   / (1270.0 * 16384.0)))

// B0 fragment layout (bytes): idx = ((((kt*4+g)*7+ct)*2+plane)*64+lane)*16+j
// B1 fragment layout (bytes): idx = (((kt*4+g)*7+ct)*64+lane)*16+j
// lane's frag byte j holds W[k = kt*64 + (lane>>4)*16 + j]
//                          [col = g*112 + ct*16 + (lane&15)]

__device__ __forceinline__ float sigmoid_f(float v) {
    return 1.0f / (1.0f + __expf(-v));
}
__device__ __forceinline__ float tanh_f(float v) {
    float e = __expf(2.0f * v);
    return 1.0f - 2.0f / (e + 1.0f);
}
// quantize a pre-scaled value to int16 and split into i8 hi/lo (hi*256+lo = a)
__device__ __forceinline__ void qsplit(float v_scaled, signed char& hi, signed char& lo) {
    int a = (int)rintf(v_scaled);
    a = a > 32639 ? 32639 : (a < -32640 ? -32640 : a);
    int l = ((a + 128) & 255) - 128;   // l in [-128,127], a-l divisible by 256
    hi = (signed char)((a - l) >> 8);
    lo = (signed char)l;
}

// async global->LDS, 16 B per lane (v6/v9/v10-validated).
__device__ __forceinline__ void gload16(const void* g, void* l) {
    __builtin_amdgcn_global_load_lds(
        (const __attribute__((address_space(1))) void*)(unsigned long long)g,
        (__attribute__((address_space(3))) void*)(unsigned)(unsigned long long)l,
        16, 0, 0);
}

// ---------------- prep: counting sort of rows by length ----------------
__global__ void k_hist(const int* __restrict__ len, int* __restrict__ hist) {
    int b = blockIdx.x * blockDim.x + threadIdx.x;
    if (b < B_) atomicAdd(&hist[len[b]], 1);
}
__global__ void k_scan(int* __restrict__ hist) {
    if (threadIdx.x == 0 && blockIdx.x == 0) {
        int acc = 0;
        for (int l = 0; l <= 100; ++l) { int c = hist[l]; hist[l] = acc; acc += c; }
    }
}
__global__ void k_scatter(const int* __restrict__ len, int* __restrict__ hist,
                          int* __restrict__ rowmap) {
    int b = blockIdx.x * blockDim.x + threadIdx.x;
    if (b < B_) {
        int pos = atomicAdd(&hist[len[b]], 1);
        rowmap[pos] = b;
    }
}

// ---------------- prep: biases (gate-major, padded) ----------------
__global__ void k_prep_bias(const float* __restrict__ bih0, const float* __restrict__ bhh0,
                            const float* __restrict__ bih1, const float* __restrict__ bhh1,
                            float* __restrict__ bias0, float* __restrict__ bias1) {
    int idx = blockIdx.x * blockDim.x + threadIdx.x;
    if (idx < 448) {
        int g = idx / 112, cell = idx % 112;
        float v0 = 0.f, v1 = 0.f;
        if (cell < 100) {
            int row = g * 100 + cell;
            v0 = bih0[row] + bhh0[row];
            v1 = bih1[row] + bhh1[row];
        }
        bias0[idx] = v0; bias1[idx] = v1;
    }
}

// ---------------- prep: weights -> fragment planes (v10, unchanged) --------
__global__ void k_prep_b_i8(const float* __restrict__ Wih0, const float* __restrict__ Whh0,
                            const float* __restrict__ Wih1, const float* __restrict__ Whh1,
                            signed char* __restrict__ B0, signed char* __restrict__ B1) {
    int idx = blockIdx.x * blockDim.x + threadIdx.x;
    if (idx >= 229376) return;                 // 114688 (L0) + 114688 (L1)
    if (idx < 114688) {                        // ---- layer 0 (int16 2-plane) ----
        int t = idx;
        int fr    = t >> 11;                   // (kt*4+g)*7 + ct
        int rem   = t & 2047;
        int plane = rem >> 10;
        int e     = rem & 1023;
        int lane = e >> 4, j = e & 15;
        int i = fr / 7, ct = fr % 7;
        int kt = i >> 2, g = i & 3;
        int k = kt * 64 + (lane >> 4) * 16 + j;
        int cell = ct * 16 + (lane & 15);
        float w = 0.f;
        if (cell < 100) {
            int row = g * 100 + cell;
            if (k < 100)      w = 2.0f * Whh0[row * 100 + k];
            else if (k < 113) w = 8.0f * Wih0[row * 13 + (k - 100)];
        }
        int a = (int)rintf(w * SB0_F);
        a = a > 32639 ? 32639 : (a < -32640 ? -32640 : a);
        int l = ((a + 128) & 255) - 128;
        B0[idx] = plane ? (signed char)l : (signed char)((a - l) >> 8);
    } else {                                   // ---- layer 1 (int8 single) ----
        int t = idx - 114688;
        int fr = t >> 10;                      // (kt*4+g)*7 + ct
        int e  = t & 1023;
        int lane = e >> 4, j = e & 15;
        int i = fr / 7, ct = fr % 7;
        int kt = i >> 2, g = i & 3;
        int k = kt * 64 + (lane >> 4) * 16 + j;
        int cell = ct * 16 + (lane & 15);
        float w = 0.f;
        if (cell < 100) {
            int row = g * 100 + cell;
            if (k < 100)      w = Wih1[row * 100 + k];
            else if (k < 200) w = Whh1[row * 100 + (k - 100)];
        }
        int a = (int)rintf(w * 1270.0f);
        a = a > 127 ? 127 : (a < -127 ? -127 : a);
        B1[t] = (signed char)a;
    }
}

// ---------------- main persistent MFMA LSTM ----------------
// v11: v10 numerics (bit-identical per gate; absmax canary 0.0002441406) with
// LAYER-PIPELINED schedule — ONE barrier per step instead of two:
//  * After the barrier publishing h0(i), BOTH next GEMMs are ready:
//    L0(i+1) needs {h0(i), x(i+1)}; L1(i) needs {h0(i), h1(i-1)}. Computing
//    them in the same phase makes them independent -> GEMM0's L2 stream
//    latency hides under GEMM1's 32 LDS-resident MFMAs; barrier count halves.
//  * Skew: prologue computes h0(0); iter i computes h0(i+1) (update if
//    i+1 < len) and h1(i) (update if i < len). Writes go to parity pn = (i&1)^1;
//    reads from p = i&1. h1(len-1) lands in A1[len&1] — readout unchanged.
//  * Wave 7 stages x(i+2) -> A0[pn] during iter i (x(0),x(1) in prologue).
//  * Register audit: both acc sets 64 + stream dbuf 16 + misc ~= 120 < 128.
// Waves 0..6: cell-tile ct, all 4 gates. Wave 7: x loader.
__global__ __attribute__((amdgpu_flat_work_group_size(512, 512), amdgpu_waves_per_eu(2, 2)))
void k_lstm(
    const float* __restrict__ x, const int* __restrict__ lengths,
    const int* __restrict__ rowmap,
    const signed char* __restrict__ B0, const signed char* __restrict__ B1,
    const float* __restrict__ bias0, const float* __restrict__ bias1,
    const float* __restrict__ Wfc, const float* __restrict__ bfc,
    float* __restrict__ out)
{
    __shared__ __align__(16) signed char Ah0[2][16 * 144];
    __shared__ __align__(16) signed char Al0[2][16 * 144];
    __shared__ __align__(16) signed char Ah1[2][16 * 272];
    __shared__ __align__(16) signed char Al1[2][16 * 272];
    __shared__ __align__(16) signed char Bres[7][16 * 1024];  // resident L1
    __shared__ int sRow[16], sLen[16], sTmax;

    const int tid = threadIdx.x;
    const int wv = tid >> 6, lane = tid & 63;

    if (tid < 16) {
        int r = rowmap[blockIdx.x * 16 + tid];
        sRow[tid] = r; sLen[tid] = lengths[r];
    }
    for (int i = tid; i < 16 * 144; i += 512) {
        Ah0[0][i] = 0; Al0[0][i] = 0; Ah0[1][i] = 0; Al0[1][i] = 0;
    }
    for (int i = tid; i < 16 * 272; i += 512) {
        Ah1[0][i] = 0; Al1[0][i] = 0; Ah1[1][i] = 0; Al1[1][i] = 0;
    }

    // ---- per-wave setup ----
    const int ct = (wv < 7) ? wv : 0, n = lane & 15, q = lane >> 4;
    const int cell = ct * 16 + n;
    const signed char* B0w = B0 + ct * 2048 + lane * 16;
    const signed char* B1w = B1 + ct * 1024 + lane * 16;

    // stage resident L1 slice (16 frags x 1 KB per wave); drained by the
    // __syncthreads before the main loop.
    if (wv < 7) {
#pragma unroll
        for (int fr = 0; fr < 16; ++fr)
            gload16(B1w + (size_t)fr * 7168, &Bres[wv][fr * 1024]);
    }
    __syncthreads();   // (pre-1) sRow/sLen + zero-init published
    if (tid == 0) { int m = 0; for (int i = 0; i < 16; ++i) m = max(m, sLen[i]); sTmax = m; }

    float b0v[4], b1v[4];
    int   lenR[4];
    float c0[4], c1[4];
    int offA0, offA1;
    if (wv < 7) {
#pragma unroll
        for (int g = 0; g < 4; ++g) {
            b0v[g] = bias0[g * 112 + cell];
            b1v[g] = bias1[g * 112 + cell];
        }
        offA0 = n * 144 + q * 16;
        offA1 = n * 272 + q * 16;
#pragma unroll
        for (int r = 0; r < 4; ++r) {
            lenR[r] = sLen[q * 4 + r];       // C row = q*4 + r
            c0[r] = 0.f; c1[r] = 0.f;
        }
    }

    // wave 7: x loader (16 rows x 13 feats = 208 slots, 4 per lane).
    // x(0) -> A0[1] (prologue GEMM0 reads A0[1]); x(1) -> A0[0] (iter 0).
    int xvalid[4]; size_t xg[4]; int xa[4]; float xv[4];
    if (wv == 7) {
#pragma unroll
        for (int i = 0; i < 4; ++i) {
            int e = i * 64 + lane;
            xvalid[i] = (e < 208);
            int r = xvalid[i] ? (e / 13) : 0;
            int f = xvalid[i] ? (e - 13 * r) : 0;
            xg[i] = (size_t)sRow[r] * (T_ * F_) + f;
            xa[i] = r * 144 + 100 + f;
            xv[i] = xvalid[i] ? x[xg[i]] : 0.f;   // t = 0
        }
#pragma unroll
        for (int i = 0; i < 4; ++i) if (xvalid[i]) {
            signed char hi, lo; qsplit(xv[i] * 4096.0f, hi, lo);
            Ah0[1][xa[i]] = hi; Al0[1][xa[i]] = lo;
        }
    }
    __syncthreads();   // (pre-2) sTmax + x(0) published
    const int Tmax = sTmax;

    // ---- prologue: GEMM0 for tau=0 (reads A0[1]: x(0), h0(-1)=0) ----
    if (wv < 7) {
        i32x4 HH[4], MM[4];
#pragma unroll
        for (int g = 0; g < 4; ++g) { HH[g] = (i32x4){0,0,0,0}; MM[g] = (i32x4){0,0,0,0}; }
        i32x4 bhi[2], blo[2], ahi, alo;
        bhi[0] = *(const i32x4*)(B0w);
        blo[0] = *(const i32x4*)(B0w + 1024);
#pragma unroll
        for (int ii = 0; ii < 8; ++ii) {
            const int kt = ii >> 2, g = ii & 3, cb = ii & 1, nbf = cb ^ 1;
            if (ii + 1 < 8) {
                bhi[nbf] = *(const i32x4*)(B0w + (size_t)(ii + 1) * 14336);
                blo[nbf] = *(const i32x4*)(B0w + (size_t)(ii + 1) * 14336 + 1024);
            }
            if (g == 0) {
                ahi = *(const i32x4*)&Ah0[1][offA0 + kt * 64];
                alo = *(const i32x4*)&Al0[1][offA0 + kt * 64];
            }
            HH[g] = __builtin_amdgcn_mfma_i32_16x16x64_i8(ahi, bhi[cb], HH[g], 0, 0, 0);
            MM[g] = __builtin_amdgcn_mfma_i32_16x16x64_i8(ahi, blo[cb], MM[g], 0, 0, 0);
            MM[g] = __builtin_amdgcn_mfma_i32_16x16x64_i8(alo, bhi[cb], MM[g], 0, 0, 0);
        }
#pragma unroll
        for (int r = 0; r < 4; ++r) {
            float zi = b0v[0] + K1_0 * (float)HH[0][r] + K2_0 * (float)MM[0][r];
            float zf = b0v[1] + K1_0 * (float)HH[1][r] + K2_0 * (float)MM[1][r];
            float zg = b0v[2] + K1_0 * (float)HH[2][r] + K2_0 * (float)MM[2][r];
            float zo = b0v[3] + K1_0 * (float)HH[3][r] + K2_0 * (float)MM[3][r];
            float cn = sigmoid_f(zf) * c0[r] + sigmoid_f(zi) * tanh_f(zg);
            float hn = sigmoid_f(zo) * tanh_f(cn);
            if (0 < lenR[r]) {
                c0[r] = cn;
                if (cell < 100) {
                    int m = q * 4 + r;
                    signed char hi, lo; qsplit(hn * 16384.0f, hi, lo);
                    Ah0[0][m * 144 + cell] = hi; Al0[0][m * 144 + cell] = lo;
                    Ah1[0][m * 272 + cell] = hi; Al1[0][m * 272 + cell] = lo;
                }
            }
        }
    } else if (wv == 7) {      // x(1) -> A0[0] (disjoint from h0 slots)
        if (1 < Tmax) {
#pragma unroll
            for (int i = 0; i < 4; ++i)
                if (xvalid[i]) xv[i] = x[xg[i] + (size_t)1 * F_];
#pragma unroll
            for (int i = 0; i < 4; ++i) if (xvalid[i]) {
                signed char hi, lo; qsplit(xv[i] * 4096.0f, hi, lo);
                Ah0[0][xa[i]] = hi; Al0[0][xa[i]] = lo;
            }
        }
    }
    __syncthreads();   // (pre-3) h0(0), x(1) published; Bres drained (vmcnt 0)

    // ---- main loop: iter i computes h0(i+1) AND h1(i), one barrier ----
    for (int i = 0; i < Tmax; ++i) {
        const int p = i & 1, pn = p ^ 1;
        if (wv < 7) {
            i32x4 H0[4], M0[4], H1[4], M1[4];
#pragma unroll
            for (int g = 0; g < 4; ++g) {
                H0[g] = (i32x4){0,0,0,0}; M0[g] = (i32x4){0,0,0,0};
                H1[g] = (i32x4){0,0,0,0}; M1[g] = (i32x4){0,0,0,0};
            }
            // GEMM0 (tau = i+1): streams B0 from L2; reads A0[p] (h0(i), x(i+1))
            // (last iter computes garbage from stale x; all its writes are
            //  guarded by i+1 < lenR <= Tmax, so it is discarded)
            i32x4 bhi[2], blo[2], a0h, a0l;
            bhi[0] = *(const i32x4*)(B0w);
            blo[0] = *(const i32x4*)(B0w + 1024);
#pragma unroll
            for (int ii = 0; ii < 8; ++ii) {
                const int kt = ii >> 2, g = ii & 3, cb = ii & 1, nbf = cb ^ 1;
                if (ii + 1 < 8) {
                    bhi[nbf] = *(const i32x4*)(B0w + (size_t)(ii + 1) * 14336);
                    blo[nbf] = *(const i32x4*)(B0w + (size_t)(ii + 1) * 14336 + 1024);
                }
                if (g == 0) {
                    a0h = *(const i32x4*)&Ah0[p][offA0 + kt * 64];
                    a0l = *(const i32x4*)&Al0[p][offA0 + kt * 64];
                }
                H0[g] = __builtin_amdgcn_mfma_i32_16x16x64_i8(a0h, bhi[cb], H0[g], 0, 0, 0);
                M0[g] = __builtin_amdgcn_mfma_i32_16x16x64_i8(a0h, blo[cb], M0[g], 0, 0, 0);
                M0[g] = __builtin_amdgcn_mfma_i32_16x16x64_i8(a0l, bhi[cb], M0[g], 0, 0, 0);
            }
            // GEMM1 (tau = i): LDS-resident B; reads A1[p] (h0(i), h1(i-1)).
            // Independent of GEMM0 -> overlaps its L2 latency.
#pragma unroll
            for (int kt = 0; kt < 4; ++kt) {
                i32x4 a1h = *(const i32x4*)&Ah1[p][offA1 + kt * 64];
                i32x4 a1l = *(const i32x4*)&Al1[p][offA1 + kt * 64];
#pragma unroll
                for (int g = 0; g < 4; ++g) {
                    i32x4 b = *(const i32x4*)&Bres[wv][(kt * 4 + g) * 1024 + lane * 16];
                    H1[g] = __builtin_amdgcn_mfma_i32_16x16x64_i8(a1h, b, H1[g], 0, 0, 0);
                    M1[g] = __builtin_amdgcn_mfma_i32_16x16x64_i8(a1l, b, M1[g], 0, 0, 0);
                }
            }
            // pointwise L0 (tau = i+1) + writes
#pragma unroll
            for (int r = 0; r < 4; ++r) {
                float zi = b0v[0] + K1_0 * (float)H0[0][r] + K2_0 * (float)M0[0][r];
                float zf = b0v[1] + K1_0 * (float)H0[1][r] + K2_0 * (float)M0[1][r];
                float zg = b0v[2] + K1_0 * (float)H0[2][r] + K2_0 * (float)M0[2][r];
                float zo = b0v[3] + K1_0 * (float)H0[3][r] + K2_0 * (float)M0[3][r];
                float cn = sigmoid_f(zf) * c0[r] + sigmoid_f(zi) * tanh_f(zg);
                float hn = sigmoid_f(zo) * tanh_f(cn);
                if (i + 1 < lenR[r]) {
                    c0[r] = cn;
                    if (cell < 100) {
                        int m = q * 4 + r;
                        signed char hi, lo; qsplit(hn * 16384.0f, hi, lo);
                        Ah0[pn][m * 144 + cell] = hi; Al0[pn][m * 144 + cell] = lo;
                        Ah1[pn][m * 272 + cell] = hi; Al1[pn][m * 272 + cell] = lo;
                    }
                }
            }
            // pointwise L1 (tau = i) + writes
#pragma unroll
            for (int r = 0; r < 4; ++r) {
                float zi = b1v[0] + K1L1 * (float)H1[0][r] + K2L1 * (float)M1[0][r];
                float zf = b1v[1] + K1L1 * (float)H1[1][r] + K2L1 * (float)M1[1][r];
                float zg = b1v[2] + K1L1 * (float)H1[2][r] + K2L1 * (float)M1[2][r];
                float zo = b1v[3] + K1L1 * (float)H1[3][r] + K2L1 * (float)M1[3][r];
                float cn = sigmoid_f(zf) * c1[r] + sigmoid_f(zi) * tanh_f(zg);
                float hn = sigmoid_f(zo) * tanh_f(cn);
                if (i < lenR[r]) {
                    c1[r] = cn;
                    if (cell < 100) {
                        int m = q * 4 + r;
                        signed char hi, lo; qsplit(hn * 16384.0f, hi, lo);
                        Ah1[pn][m * 272 + 100 + cell] = hi;
                        Al1[pn][m * 272 + 100 + cell] = lo;
                    }
                }
            }
        } else if (wv == 7) {
            // stage x(i+2) -> A0[pn] (read at iter i+1)
            if (i + 2 < Tmax) {
#pragma unroll
                for (int k = 0; k < 4; ++k)
                    if (xvalid[k]) xv[k] = x[xg[k] + (size_t)(i + 2) * F_];
#pragma unroll
                for (int k = 0; k < 4; ++k) if (xvalid[k]) {
                    signed char hi, lo; qsplit(xv[k] * 4096.0f, hi, lo);
                    Ah0[pn][xa[k]] = hi; Al0[pn][xa[k]] = lo;
                }
            }
        }
        __syncthreads();   // single barrier: h0(i+1), h1(i), x(i+2) published
    }

    // final: out[b] = W_fc . h1 + b_fc; h1 (int16 repr of h/2) lives in
    // buffer len&1 (last h1 write at iter len-1 targeted parity len&1)
    if (tid < 16) {
        const int par = sLen[tid] & 1;
        float s = bfc[0];
        for (int j = 0; j < 100; ++j) {
            int a = ((int)Ah1[par][tid * 272 + 100 + j]) * 256 +
                    (int)Al1[par][tid * 272 + 100 + j];
            float h = (float)a * (1.0f / 16384.0f);
            s = fmaf(Wfc[j], h, s);
        }
        out[sRow[tid]] = s;
    }
}

// ---------------- launch ----------------
extern "C" void kernel_launch(void* const* d_in, const int* in_sizes, int n_in,
                              void* d_out, int out_size, void* d_ws, size_t ws_size,
                              hipStream_t stream) {
    const float* x    = (const float*)d_in[0];
    const int*   len  = (const int*)d_in[1];
    const float* Wih0 = (const float*)d_in[2];
    const float* Whh0 = (const float*)d_in[3];
    const float* bih0 = (const float*)d_in[4];
    const float* bhh0 = (const float*)d_in[5];
    const float* Wih1 = (const float*)d_in[6];
    const float* Whh1 = (const float*)d_in[7];
    const float* bih1 = (const float*)d_in[8];
    const float* bhh1 = (const float*)d_in[9];
    const float* Wfc  = (const float*)d_in[10];
    const float* bfc  = (const float*)d_in[11];
    float* out = (float*)d_out;

    char* ws = (char*)d_ws;   // uses 249,856 bytes
    int*         hist   = (int*)(ws + O_HIST);
    int*         rowmap = (int*)(ws + O_ROWMAP);
    float*       bias0  = (float*)(ws + O_BIAS0);
    float*       bias1  = (float*)(ws + O_BIAS1);
    signed char* B0     = (signed char*)(ws + O_B0);
    signed char* B1     = (signed char*)(ws + O_B1);

    hipMemsetAsync(hist, 0, 512, stream);
    k_hist<<<16, 256, 0, stream>>>(len, hist);
    k_scan<<<1, 64, 0, stream>>>(hist);
    k_scatter<<<16, 256, 0, stream>>>(len, hist, rowmap);
    k_prep_bias<<<2, 256, 0, stream>>>(bih0, bhh0, bih1, bhh1, bias0, bias1);
    k_prep_b_i8<<<896, 256, 0, stream>>>(Wih0, Whh0, Wih1, Whh1, B0, B1);
    k_lstm<<<256, 512, 0, stream>>>(x, len, rowmap, B0, B1, bias0, bias1, Wfc, bfc, out);
}

// Round 11
// 537.873 us; speedup vs baseline: 1.2942x; 1.1194x over previous
//
#include <hip/hip_runtime.h>
#include <math.h>

// Problem constants (B=4096, T=100, F=13, H=100)
#define B_    4096
#define T_    100
#define F_    13
#define H_    100

typedef int   i32x4 __attribute__((ext_vector_type(4)));
typedef float f32x4 __attribute__((ext_vector_type(4)));

// ---- ws layout (bytes), total 249,856 ----
#define O_HIST   0u        // 512
#define O_ROWMAP 512u      // 4096*4
#define O_BIAS0  16896u    // 448*4
#define O_BIAS1  18688u    // 448*4
#define O_B0     20480u    // L0 int16-as-2xi8: 2kt*4g*7ct*2pl*1024 = 114688
#define O_B1     135168u   // L1 int8 single plane: 4kt*4g*7ct*1024 = 114688 -> 249856

// ---- quantization scheme (v10/v11, unchanged in v12) ----
// State (A): int16 as two i8 planes (hi*256+lo), scale 1/32768 of stored val:
//   h stored as h/2 (a = rint(h*16384)); x stored as x/8 (a = rint(x*4096)).
// L0 weights (B0): int16 = rint(w_eff*40000), i8 hi/lo planes:
//   w_eff = 2*Whh0 (h cols) or 8*Wih0 (x cols)
//   z0 = bias + K1_0*(Ahi.Bhi) + K2_0*(Ahi.Blo + Alo.Bhi)  [Alo.Blo dropped]
// L1 weights (B1): int8 single plane w_int = rint(w*1270), LDS-resident.
//   z1 = bias + K1L1*(Ahi.B) + K2L1*(Alo.B)
#define SB0_F  40000.0f
#define K1_0   ((float)(65536.0 / (32768.0 * 40000.0)))
#define K2_0   ((float)(256.0   / (32768.0 * 40000.0)))
#define K1L1   ((float)(256.0 / (1270.0 * 16384.0)))
#define K2L1   ((float)(1.0   / (1270.0 * 16384.0)))

// B0 fragment layout (bytes): idx = ((((kt*4+g)*7+ct)*2+plane)*64+lane)*16+j
// B1 fragment layout (bytes): idx = (((kt*4+g)*7+ct)*64+lane)*16+j
// lane's frag byte j holds W[k = kt*64 + (lane>>4)*16 + j]
//                          [col = g*112 + ct*16 + (lane&15)]

__device__ __forceinline__ float sigmoid_f(float v) {
    return 1.0f / (1.0f + __expf(-v));
}
__device__ __forceinline__ float tanh_f(float v) {
    float e = __expf(2.0f * v);
    return 1.0f - 2.0f / (e + 1.0f);
}
// quantize with clamp (loader path; x can exceed range)
__device__ __forceinline__ void qsplit(float v_scaled, signed char& hi, signed char& lo) {
    int a = (int)rintf(v_scaled);
    a = a > 32639 ? 32639 : (a < -32640 ? -32640 : a);
    int l = ((a + 128) & 255) - 128;   // sign-extended low byte
    hi = (signed char)((a - l) >> 8);
    lo = (signed char)l;
}
// lean quantize for h (|h|<1 -> |a|<=16384: clamp provably dead, bit-identical)
__device__ __forceinline__ void qsplit_h(float v_scaled, signed char& hi, signed char& lo) {
    int a = (int)rintf(v_scaled);
    int l = ((a + 128) & 255) - 128;
    hi = (signed char)((a - l) >> 8);
    lo = (signed char)l;
}

// async global->LDS, 16 B per lane (v6/v9/v10-validated).
__device__ __forceinline__ void gload16(const void* g, void* l) {
    __builtin_amdgcn_global_load_lds(
        (const __attribute__((address_space(1))) void*)(unsigned long long)g,
        (__attribute__((address_space(3))) void*)(unsigned)(unsigned long long)l,
        16, 0, 0);
}

// ---------------- prep: counting sort of rows by length ----------------
__global__ void k_hist(const int* __restrict__ len, int* __restrict__ hist) {
    int b = blockIdx.x * blockDim.x + threadIdx.x;
    if (b < B_) atomicAdd(&hist[len[b]], 1);
}
__global__ void k_scan(int* __restrict__ hist) {
    if (threadIdx.x == 0 && blockIdx.x == 0) {
        int acc = 0;
        for (int l = 0; l <= 100; ++l) { int c = hist[l]; hist[l] = acc; acc += c; }
    }
}
__global__ void k_scatter(const int* __restrict__ len, int* __restrict__ hist,
                          int* __restrict__ rowmap) {
    int b = blockIdx.x * blockDim.x + threadIdx.x;
    if (b < B_) {
        int pos = atomicAdd(&hist[len[b]], 1);
        rowmap[pos] = b;
    }
}

// ---------------- prep: biases (gate-major, padded) ----------------
__global__ void k_prep_bias(const float* __restrict__ bih0, const float* __restrict__ bhh0,
                            const float* __restrict__ bih1, const float* __restrict__ bhh1,
                            float* __restrict__ bias0, float* __restrict__ bias1) {
    int idx = blockIdx.x * blockDim.x + threadIdx.x;
    if (idx < 448) {
        int g = idx / 112, cell = idx % 112;
        float v0 = 0.f, v1 = 0.f;
        if (cell < 100) {
            int row = g * 100 + cell;
            v0 = bih0[row] + bhh0[row];
            v1 = bih1[row] + bhh1[row];
        }
        bias0[idx] = v0; bias1[idx] = v1;
    }
}

// ---------------- prep: weights -> fragment planes (v10, unchanged) --------
__global__ void k_prep_b_i8(const float* __restrict__ Wih0, const float* __restrict__ Whh0,
                            const float* __restrict__ Wih1, const float* __restrict__ Whh1,
                            signed char* __restrict__ B0, signed char* __restrict__ B1) {
    int idx = blockIdx.x * blockDim.x + threadIdx.x;
    if (idx >= 229376) return;                 // 114688 (L0) + 114688 (L1)
    if (idx < 114688) {                        // ---- layer 0 (int16 2-plane) ----
        int t = idx;
        int fr    = t >> 11;                   // (kt*4+g)*7 + ct
        int rem   = t & 2047;
        int plane = rem >> 10;
        int e     = rem & 1023;
        int lane = e >> 4, j = e & 15;
        int i = fr / 7, ct = fr % 7;
        int kt = i >> 2, g = i & 3;
        int k = kt * 64 + (lane >> 4) * 16 + j;
        int cell = ct * 16 + (lane & 15);
        float w = 0.f;
        if (cell < 100) {
            int row = g * 100 + cell;
            if (k < 100)      w = 2.0f * Whh0[row * 100 + k];
            else if (k < 113) w = 8.0f * Wih0[row * 13 + (k - 100)];
        }
        int a = (int)rintf(w * SB0_F);
        a = a > 32639 ? 32639 : (a < -32640 ? -32640 : a);
        int l = ((a + 128) & 255) - 128;
        B0[idx] = plane ? (signed char)l : (signed char)((a - l) >> 8);
    } else {                                   // ---- layer 1 (int8 single) ----
        int t = idx - 114688;
        int fr = t >> 10;                      // (kt*4+g)*7 + ct
        int e  = t & 1023;
        int lane = e >> 4, j = e & 15;
        int i = fr / 7, ct = fr % 7;
        int kt = i >> 2, g = i & 3;
        int k = kt * 64 + (lane >> 4) * 16 + j;
        int cell = ct * 16 + (lane & 15);
        float w = 0.f;
        if (cell < 100) {
            int row = g * 100 + cell;
            if (k < 100)      w = Wih1[row * 100 + k];
            else if (k < 200) w = Whh1[row * 100 + (k - 100)];
        }
        int a = (int)rintf(w * 1270.0f);
        a = a > 127 ? 127 : (a < -127 ? -127 : a);
        B1[t] = (signed char)a;
    }
}

// ---------------- main persistent MFMA LSTM ----------------
// v12: v11 numerics (bit-identical; absmax canary 0.0002441406), reordered
// fused step to overlap VALU with the L2 stream (busy-CU profile: VALU ~58%,
// the true bottleneck after occupancy-dilution correction):
//   per iter: [issue B0 pairs 0..3 (4-slot reg rotation, 32 VGPR)]
//             -> GEMM1 (LDS-resident MFMAs)
//             -> pointwise L1 + h1 writes        (covers B0 pairs 0-3 latency)
//             -> GEMM0 (consume slots, prefetch ii+4)
//             -> pointwise L0 + h0 writes
//             -> single barrier.
//   H1/M1 retire before H0/M0 go live -> lower peak register pressure.
// Plus VALU cuts: lean qsplit_h (clamp dead for |h|<1), branchless c-select.
// Waves 0..6: cell-tile ct, all 4 gates. Wave 7: x loader.
__global__ __attribute__((amdgpu_flat_work_group_size(512, 512), amdgpu_waves_per_eu(2, 2)))
void k_lstm(
    const float* __restrict__ x, const int* __restrict__ lengths,
    const int* __restrict__ rowmap,
    const signed char* __restrict__ B0, const signed char* __restrict__ B1,
    const float* __restrict__ bias0, const float* __restrict__ bias1,
    const float* __restrict__ Wfc, const float* __restrict__ bfc,
    float* __restrict__ out)
{
    __shared__ __align__(16) signed char Ah0[2][16 * 144];
    __shared__ __align__(16) signed char Al0[2][16 * 144];
    __shared__ __align__(16) signed char Ah1[2][16 * 272];
    __shared__ __align__(16) signed char Al1[2][16 * 272];
    __shared__ __align__(16) signed char Bres[7][16 * 1024];  // resident L1
    __shared__ int sRow[16], sLen[16], sTmax;

    const int tid = threadIdx.x;
    const int wv = tid >> 6, lane = tid & 63;

    if (tid < 16) {
        int r = rowmap[blockIdx.x * 16 + tid];
        sRow[tid] = r; sLen[tid] = lengths[r];
    }
    for (int i = tid; i < 16 * 144; i += 512) {
        Ah0[0][i] = 0; Al0[0][i] = 0; Ah0[1][i] = 0; Al0[1][i] = 0;
    }
    for (int i = tid; i < 16 * 272; i += 512) {
        Ah1[0][i] = 0; Al1[0][i] = 0; Ah1[1][i] = 0; Al1[1][i] = 0;
    }

    // ---- per-wave setup ----
    const int ct = (wv < 7) ? wv : 0, n = lane & 15, q = lane >> 4;
    const int cell = ct * 16 + n;
    const signed char* B0w = B0 + ct * 2048 + lane * 16;
    const signed char* B1w = B1 + ct * 1024 + lane * 16;

    // stage resident L1 slice (16 frags x 1 KB per wave)
    if (wv < 7) {
#pragma unroll
        for (int fr = 0; fr < 16; ++fr)
            gload16(B1w + (size_t)fr * 7168, &Bres[wv][fr * 1024]);
    }
    __syncthreads();   // (pre-1) sRow/sLen + zero-init published
    if (tid == 0) { int m = 0; for (int i = 0; i < 16; ++i) m = max(m, sLen[i]); sTmax = m; }

    float b0v[4], b1v[4];
    int   lenR[4];
    float c0[4], c1[4];
    int offA0, offA1;
    if (wv < 7) {
#pragma unroll
        for (int g = 0; g < 4; ++g) {
            b0v[g] = bias0[g * 112 + cell];
            b1v[g] = bias1[g * 112 + cell];
        }
        offA0 = n * 144 + q * 16;
        offA1 = n * 272 + q * 16;
#pragma unroll
        for (int r = 0; r < 4; ++r) {
            lenR[r] = sLen[q * 4 + r];       // C row = q*4 + r
            c0[r] = 0.f; c1[r] = 0.f;
        }
    }

    // wave 7: x loader. x(0) -> A0[1]; x(1) -> A0[0].
    int xvalid[4]; size_t xg[4]; int xa[4]; float xv[4];
    if (wv == 7) {
#pragma unroll
        for (int i = 0; i < 4; ++i) {
            int e = i * 64 + lane;
            xvalid[i] = (e < 208);
            int r = xvalid[i] ? (e / 13) : 0;
            int f = xvalid[i] ? (e - 13 * r) : 0;
            xg[i] = (size_t)sRow[r] * (T_ * F_) + f;
            xa[i] = r * 144 + 100 + f;
            xv[i] = xvalid[i] ? x[xg[i]] : 0.f;   // t = 0
        }
#pragma unroll
        for (int i = 0; i < 4; ++i) if (xvalid[i]) {
            signed char hi, lo; qsplit(xv[i] * 4096.0f, hi, lo);
            Ah0[1][xa[i]] = hi; Al0[1][xa[i]] = lo;
        }
    }
    __syncthreads();   // (pre-2) sTmax + x(0) published
    const int Tmax = sTmax;

    // ---- prologue: GEMM0 for tau=0 (reads A0[1]: x(0), h0(-1)=0) ----
    if (wv < 7) {
        i32x4 HH[4], MM[4];
#pragma unroll
        for (int g = 0; g < 4; ++g) { HH[g] = (i32x4){0,0,0,0}; MM[g] = (i32x4){0,0,0,0}; }
        i32x4 bhi[2], blo[2], ahi, alo;
        bhi[0] = *(const i32x4*)(B0w);
        blo[0] = *(const i32x4*)(B0w + 1024);
#pragma unroll
        for (int ii = 0; ii < 8; ++ii) {
            const int kt = ii >> 2, g = ii & 3, cb = ii & 1, nbf = cb ^ 1;
            if (ii + 1 < 8) {
                bhi[nbf] = *(const i32x4*)(B0w + (size_t)(ii + 1) * 14336);
                blo[nbf] = *(const i32x4*)(B0w + (size_t)(ii + 1) * 14336 + 1024);
            }
            if (g == 0) {
                ahi = *(const i32x4*)&Ah0[1][offA0 + kt * 64];
                alo = *(const i32x4*)&Al0[1][offA0 + kt * 64];
            }
            HH[g] = __builtin_amdgcn_mfma_i32_16x16x64_i8(ahi, bhi[cb], HH[g], 0, 0, 0);
            MM[g] = __builtin_amdgcn_mfma_i32_16x16x64_i8(ahi, blo[cb], MM[g], 0, 0, 0);
            MM[g] = __builtin_amdgcn_mfma_i32_16x16x64_i8(alo, bhi[cb], MM[g], 0, 0, 0);
        }
#pragma unroll
        for (int r = 0; r < 4; ++r) {
            float zi = b0v[0] + K1_0 * (float)HH[0][r] + K2_0 * (float)MM[0][r];
            float zf = b0v[1] + K1_0 * (float)HH[1][r] + K2_0 * (float)MM[1][r];
            float zg = b0v[2] + K1_0 * (float)HH[2][r] + K2_0 * (float)MM[2][r];
            float zo = b0v[3] + K1_0 * (float)HH[3][r] + K2_0 * (float)MM[3][r];
            float cn = sigmoid_f(zf) * c0[r] + sigmoid_f(zi) * tanh_f(zg);
            float hn = sigmoid_f(zo) * tanh_f(cn);
            if (0 < lenR[r]) {
                c0[r] = cn;
                if (cell < 100) {
                    int m = q * 4 + r;
                    signed char hi, lo; qsplit_h(hn * 16384.0f, hi, lo);
                    Ah0[0][m * 144 + cell] = hi; Al0[0][m * 144 + cell] = lo;
                    Ah1[0][m * 272 + cell] = hi; Al1[0][m * 272 + cell] = lo;
                }
            }
        }
    } else if (wv == 7) {      // x(1) -> A0[0]
        if (1 < Tmax) {
#pragma unroll
            for (int i = 0; i < 4; ++i)
                if (xvalid[i]) xv[i] = x[xg[i] + (size_t)1 * F_];
#pragma unroll
            for (int i = 0; i < 4; ++i) if (xvalid[i]) {
                signed char hi, lo; qsplit(xv[i] * 4096.0f, hi, lo);
                Ah0[0][xa[i]] = hi; Al0[0][xa[i]] = lo;
            }
        }
    }
    __syncthreads();   // (pre-3) h0(0), x(1) published; Bres drained

    // ---- main loop: iter i computes h1(i) then h0(i+1); one barrier ----
    for (int i = 0; i < Tmax; ++i) {
        const int p = i & 1, pn = p ^ 1;
        if (wv < 7) {
            // --- issue B0 pairs 0..3 (4-slot rotation) before any compute ---
            i32x4 bhi[4], blo[4];
#pragma unroll
            for (int s = 0; s < 4; ++s) {
                bhi[s] = *(const i32x4*)(B0w + (size_t)s * 14336);
                blo[s] = *(const i32x4*)(B0w + (size_t)s * 14336 + 1024);
            }
            // --- GEMM1 (tau = i): LDS-resident B; reads A1[p] ---
            i32x4 H1[4], M1[4];
#pragma unroll
            for (int g = 0; g < 4; ++g) { H1[g] = (i32x4){0,0,0,0}; M1[g] = (i32x4){0,0,0,0}; }
#pragma unroll
            for (int kt = 0; kt < 4; ++kt) {
                i32x4 a1h = *(const i32x4*)&Ah1[p][offA1 + kt * 64];
                i32x4 a1l = *(const i32x4*)&Al1[p][offA1 + kt * 64];
#pragma unroll
                for (int g = 0; g < 4; ++g) {
                    i32x4 b = *(const i32x4*)&Bres[wv][(kt * 4 + g) * 1024 + lane * 16];
                    H1[g] = __builtin_amdgcn_mfma_i32_16x16x64_i8(a1h, b, H1[g], 0, 0, 0);
                    M1[g] = __builtin_amdgcn_mfma_i32_16x16x64_i8(a1l, b, M1[g], 0, 0, 0);
                }
            }
            // --- pointwise L1 (tau = i) + h1 writes (covers B0 latency) ---
#pragma unroll
            for (int r = 0; r < 4; ++r) {
                float zi = b1v[0] + K1L1 * (float)H1[0][r] + K2L1 * (float)M1[0][r];
                float zf = b1v[1] + K1L1 * (float)H1[1][r] + K2L1 * (float)M1[1][r];
                float zg = b1v[2] + K1L1 * (float)H1[2][r] + K2L1 * (float)M1[2][r];
                float zo = b1v[3] + K1L1 * (float)H1[3][r] + K2L1 * (float)M1[3][r];
                float cn = sigmoid_f(zf) * c1[r] + sigmoid_f(zi) * tanh_f(zg);
                float hn = sigmoid_f(zo) * tanh_f(cn);
                const bool upd = (i < lenR[r]);
                c1[r] = upd ? cn : c1[r];
                if (upd && cell < 100) {
                    int m = q * 4 + r;
                    signed char hi, lo; qsplit_h(hn * 16384.0f, hi, lo);
                    Ah1[pn][m * 272 + 100 + cell] = hi;
                    Al1[pn][m * 272 + 100 + cell] = lo;
                }
            }
            // --- GEMM0 (tau = i+1): reads A0[p]; consume slots, prefetch +4 ---
            i32x4 H0[4], M0[4];
#pragma unroll
            for (int g = 0; g < 4; ++g) { H0[g] = (i32x4){0,0,0,0}; M0[g] = (i32x4){0,0,0,0}; }
            i32x4 a0h, a0l;
#pragma unroll
            for (int ii = 0; ii < 8; ++ii) {
                const int kt = ii >> 2, g = ii & 3, s = ii & 3;
                if (g == 0) {
                    a0h = *(const i32x4*)&Ah0[p][offA0 + kt * 64];
                    a0l = *(const i32x4*)&Al0[p][offA0 + kt * 64];
                }
                H0[g] = __builtin_amdgcn_mfma_i32_16x16x64_i8(a0h, bhi[s], H0[g], 0, 0, 0);
                M0[g] = __builtin_amdgcn_mfma_i32_16x16x64_i8(a0h, blo[s], M0[g], 0, 0, 0);
                M0[g] = __builtin_amdgcn_mfma_i32_16x16x64_i8(a0l, bhi[s], M0[g], 0, 0, 0);
                if (ii + 4 < 8) {              // refill just-freed slot
                    bhi[s] = *(const i32x4*)(B0w + (size_t)(ii + 4) * 14336);
                    blo[s] = *(const i32x4*)(B0w + (size_t)(ii + 4) * 14336 + 1024);
                }
            }
            // --- pointwise L0 (tau = i+1) + h0 writes ---
#pragma unroll
            for (int r = 0; r < 4; ++r) {
                float zi = b0v[0] + K1_0 * (float)H0[0][r] + K2_0 * (float)M0[0][r];
                float zf = b0v[1] + K1_0 * (float)H0[1][r] + K2_0 * (float)M0[1][r];
                float zg = b0v[2] + K1_0 * (float)H0[2][r] + K2_0 * (float)M0[2][r];
                float zo = b0v[3] + K1_0 * (float)H0[3][r] + K2_0 * (float)M0[3][r];
                float cn = sigmoid_f(zf) * c0[r] + sigmoid_f(zi) * tanh_f(zg);
                float hn = sigmoid_f(zo) * tanh_f(cn);
                const bool upd = (i + 1 < lenR[r]);
                c0[r] = upd ? cn : c0[r];
                if (upd && cell < 100) {
                    int m = q * 4 + r;
                    signed char hi, lo; qsplit_h(hn * 16384.0f, hi, lo);
                    Ah0[pn][m * 144 + cell] = hi; Al0[pn][m * 144 + cell] = lo;
                    Ah1[pn][m * 272 + cell] = hi; Al1[pn][m * 272 + cell] = lo;
                }
            }
        } else if (wv == 7) {
            // stage x(i+2) -> A0[pn] (read at iter i+1)
            if (i + 2 < Tmax) {
#pragma unroll
                for (int k = 0; k < 4; ++k)
                    if (xvalid[k]) xv[k] = x[xg[k] + (size_t)(i + 2) * F_];
#pragma unroll
                for (int k = 0; k < 4; ++k) if (xvalid[k]) {
                    signed char hi, lo; qsplit(xv[k] * 4096.0f, hi, lo);
                    Ah0[pn][xa[k]] = hi; Al0[pn][xa[k]] = lo;
                }
            }
        }
        __syncthreads();   // single barrier: h0(i+1), h1(i), x(i+2) published
    }

    // final: out[b] = W_fc . h1 + b_fc; h1 (int16 repr of h/2) lives in
    // buffer len&1 (last h1 write at iter len-1 targeted parity len&1)
    if (tid < 16) {
        const int par = sLen[tid] & 1;
        float s = bfc[0];
        for (int j = 0; j < 100; ++j) {
            int a = ((int)Ah1[par][tid * 272 + 100 + j]) * 256 +
                    (int)Al1[par][tid * 272 + 100 + j];
            float h = (float)a * (1.0f / 16384.0f);
            s = fmaf(Wfc[j], h, s);
        }
        out[sRow[tid]] = s;
    }
}

// ---------------- launch ----------------
extern "C" void kernel_launch(void* const* d_in, const int* in_sizes, int n_in,
                              void* d_out, int out_size, void* d_ws, size_t ws_size,
                              hipStream_t stream) {
    const float* x    = (const float*)d_in[0];
    const int*   len  = (const int*)d_in[1];
    const float* Wih0 = (const float*)d_in[2];
    const float* Whh0 = (const float*)d_in[3];
    const float* bih0 = (const float*)d_in[4];
    const float* bhh0 = (const float*)d_in[5];
    const float* Wih1 = (const float*)d_in[6];
    const float* Whh1 = (const float*)d_in[7];
    const float* bih1 = (const float*)d_in[8];
    const float* bhh1 = (const float*)d_in[9];
    const float* Wfc  = (const float*)d_in[10];
    const float* bfc  = (const float*)d_in[11];
    float* out = (float*)d_out;

    char* ws = (char*)d_ws;   // uses 249,856 bytes
    int*         hist   = (int*)(ws + O_HIST);
    int*         rowmap = (int*)(ws + O_ROWMAP);
    float*       bias0  = (float*)(ws + O_BIAS0);
    float*       bias1  = (float*)(ws + O_BIAS1);
    signed char* B0     = (signed char*)(ws + O_B0);
    signed char* B1     = (signed char*)(ws + O_B1);

    hipMemsetAsync(hist, 0, 512, stream);
    k_hist<<<16, 256, 0, stream>>>(len, hist);
    k_scan<<<1, 64, 0, stream>>>(hist);
    k_scatter<<<16, 256, 0, stream>>>(len, hist, rowmap);
    k_prep_bias<<<2, 256, 0, stream>>>(bih0, bhh0, bih1, bhh1, bias0, bias1);
    k_prep_b_i8<<<896, 256, 0, stream>>>(Wih0, Whh0, Wih1, Whh1, B0, B1);
    k_lstm<<<256, 512, 0, stream>>>(x, len, rowmap, B0, B1, bias0, bias1, Wfc, bfc, out);
}

// Round 12
// 519.583 us; speedup vs baseline: 1.3398x; 1.0352x over previous
//
#include <hip/hip_runtime.h>
#include <math.h>

// Problem constants (B=4096, T=100, F=13, H=100)
#define B_    4096
#define T_    100
#define F_    13
#define H_    100

typedef int   i32x4 __attribute__((ext_vector_type(4)));
typedef float f32x4 __attribute__((ext_vector_type(4)));

// ---- ws layout (bytes), total 249,856 ----
#define O_HIST   0u        // 512
#define O_ROWMAP 512u      // 4096*4
#define O_BIAS0  16896u    // 448*4
#define O_BIAS1  18688u    // 448*4
#define O_B0     20480u    // L0 int16-as-2xi8: 2kt*4g*7ct*2pl*1024 = 114688
#define O_B1     135168u   // L1 int8 single plane: 4kt*4g*7ct*1024 = 114688 -> 249856

// ---- quantization scheme (v10/v11/v12; v13 merges the K1/K2 reduction) ----
// State (A): int16 as two i8 planes (hi*256+lo), scale 1/32768 of stored val:
//   h stored as h/2 (a = rint(h*16384)); x stored as x/8 (a = rint(x*4096)).
// L0 weights (B0): int16 = rint(w_eff*40000), i8 hi/lo planes:
//   w_eff = 2*Whh0 (h cols) or 8*Wih0 (x cols)
//   z0 = bias + KM0*(256*(Ahi.Bhi) + (Ahi.Blo + Alo.Bhi))   [Alo.Blo dropped]
// L1 weights (B1): int8 single plane w_int = rint(w*1270), LDS-resident.
//   z1 = bias + KM1*(256*(Ahi.B) + (Alo.B))
// (K1 = 256*K2 exactly in both layers -> single merged constant KM;
//  int merge T = (H<<8)+M is overflow-safe: |T| <= ~4.8e8 < 2^31.)
#define SB0_F  40000.0f
#define KM0  ((float)(256.0 / (32768.0 * 40000.0)))
#define KM1  ((float)(1.0   / (1270.0 * 16384.0)))
// sigmoid consumes exp(-z): fold NEGATED constants; tanh consumes exp(2z):
// fold DOUBLED constants (negation / pow2-scale are IEEE-exact).
#define NK0  (-KM0)
#define DK0  (2.0f * KM0)
#define NK1  (-KM1)
#define DK1  (2.0f * KM1)

// B0 fragment layout (bytes): idx = ((((kt*4+g)*7+ct)*2+plane)*64+lane)*16+j
// B1 fragment layout (bytes): idx = (((kt*4+g)*7+ct)*64+lane)*16+j
// lane's frag byte j holds W[k = kt*64 + (lane>>4)*16 + j]
//                          [col = g*112 + ct*16 + (lane&15)]

__device__ __forceinline__ float tanh_f(float v) {
    float e = __expf(2.0f * v);
    return 1.0f - 2.0f / (e + 1.0f);
}
// quantize with clamp (x loader path; x can exceed range)
__device__ __forceinline__ void qsplit(float v_scaled, signed char& hi, signed char& lo) {
    int a = (int)rintf(v_scaled);
    a = a > 32639 ? 32639 : (a < -32640 ? -32640 : a);
    int l = (int)(signed char)(a & 0xFF);
    hi = (signed char)((a - l) >> 8);
    lo = (signed char)l;
}
// lean quantize for h (|h|<1 -> |a|<=16384: clamp dead; sext low byte via bfe)
__device__ __forceinline__ void qsplit_h(float v_scaled, signed char& hi, signed char& lo) {
    int a = (int)rintf(v_scaled);
    int l = (int)(signed char)(a & 0xFF);
    hi = (signed char)((a - l) >> 8);
    lo = (signed char)l;
}

// async global->LDS, 16 B per lane (v6/v9/v10-validated).
__device__ __forceinline__ void gload16(const void* g, void* l) {
    __builtin_amdgcn_global_load_lds(
        (const __attribute__((address_space(1))) void*)(unsigned long long)g,
        (__attribute__((address_space(3))) void*)(unsigned)(unsigned long long)l,
        16, 0, 0);
}

// ---------------- prep: counting sort of rows by length ----------------
__global__ void k_hist(const int* __restrict__ len, int* __restrict__ hist) {
    int b = blockIdx.x * blockDim.x + threadIdx.x;
    if (b < B_) atomicAdd(&hist[len[b]], 1);
}
__global__ void k_scan(int* __restrict__ hist) {
    if (threadIdx.x == 0 && blockIdx.x == 0) {
        int acc = 0;
        for (int l = 0; l <= 100; ++l) { int c = hist[l]; hist[l] = acc; acc += c; }
    }
}
__global__ void k_scatter(const int* __restrict__ len, int* __restrict__ hist,
                          int* __restrict__ rowmap) {
    int b = blockIdx.x * blockDim.x + threadIdx.x;
    if (b < B_) {
        int pos = atomicAdd(&hist[len[b]], 1);
        rowmap[pos] = b;
    }
}

// ---------------- prep: biases (gate-major, padded) ----------------
__global__ void k_prep_bias(const float* __restrict__ bih0, const float* __restrict__ bhh0,
                            const float* __restrict__ bih1, const float* __restrict__ bhh1,
                            float* __restrict__ bias0, float* __restrict__ bias1) {
    int idx = blockIdx.x * blockDim.x + threadIdx.x;
    if (idx < 448) {
        int g = idx / 112, cell = idx % 112;
        float v0 = 0.f, v1 = 0.f;
        if (cell < 100) {
            int row = g * 100 + cell;
            v0 = bih0[row] + bhh0[row];
            v1 = bih1[row] + bhh1[row];
        }
        bias0[idx] = v0; bias1[idx] = v1;
    }
}

// ---------------- prep: weights -> fragment planes (v10, unchanged) --------
__global__ void k_prep_b_i8(const float* __restrict__ Wih0, const float* __restrict__ Whh0,
                            const float* __restrict__ Wih1, const float* __restrict__ Whh1,
                            signed char* __restrict__ B0, signed char* __restrict__ B1) {
    int idx = blockIdx.x * blockDim.x + threadIdx.x;
    if (idx >= 229376) return;                 // 114688 (L0) + 114688 (L1)
    if (idx < 114688) {                        // ---- layer 0 (int16 2-plane) ----
        int t = idx;
        int fr    = t >> 11;                   // (kt*4+g)*7 + ct
        int rem   = t & 2047;
        int plane = rem >> 10;
        int e     = rem & 1023;
        int lane = e >> 4, j = e & 15;
        int i = fr / 7, ct = fr % 7;
        int kt = i >> 2, g = i & 3;
        int k = kt * 64 + (lane >> 4) * 16 + j;
        int cell = ct * 16 + (lane & 15);
        float w = 0.f;
        if (cell < 100) {
            int row = g * 100 + cell;
            if (k < 100)      w = 2.0f * Whh0[row * 100 + k];
            else if (k < 113) w = 8.0f * Wih0[row * 13 + (k - 100)];
        }
        int a = (int)rintf(w * SB0_F);
        a = a > 32639 ? 32639 : (a < -32640 ? -32640 : a);
        int l = ((a + 128) & 255) - 128;
        B0[idx] = plane ? (signed char)l : (signed char)((a - l) >> 8);
    } else {                                   // ---- layer 1 (int8 single) ----
        int t = idx - 114688;
        int fr = t >> 10;                      // (kt*4+g)*7 + ct
        int e  = t & 1023;
        int lane = e >> 4, j = e & 15;
        int i = fr / 7, ct = fr % 7;
        int kt = i >> 2, g = i & 3;
        int k = kt * 64 + (lane >> 4) * 16 + j;
        int cell = ct * 16 + (lane & 15);
        float w = 0.f;
        if (cell < 100) {
            int row = g * 100 + cell;
            if (k < 100)      w = Wih1[row * 100 + k];
            else if (k < 200) w = Whh1[row * 100 + (k - 100)];
        }
        int a = (int)rintf(w * 1270.0f);
        a = a > 127 ? 127 : (a < -127 ? -127 : a);
        B1[t] = (signed char)a;
    }
}

// ---------------- main persistent MFMA LSTM ----------------
// v13: v12 structure + VALU diet (busy-CU VALU ~66% was the bottleneck):
//  * t-loop unrolled x2: parity is a compile-time literal in each body ->
//    all LDS addresses loop-invariant / immediate-offset (no per-step
//    p*stride recomputation).
//  * int-merge: z = bias + KM*(float)((H<<8)+M) — K1=256*K2 exactly, so one
//    lshl_add+cvt+fma replaces 2 cvt + 2 fma per gate. Overflow-audited.
//  * sign/scale folding: sigmoid path uses pre-negated (bias, KM); tanh path
//    pre-doubled — both IEEE-exact rewrites, removing negate/double ops.
//  * lean qsplit_h via sext-low-byte (v_bfe).
// Waves 0..6: cell-tile ct, all 4 gates. Wave 7: x loader.
__global__ __attribute__((amdgpu_flat_work_group_size(512, 512), amdgpu_waves_per_eu(2, 2)))
void k_lstm(
    const float* __restrict__ x, const int* __restrict__ lengths,
    const int* __restrict__ rowmap,
    const signed char* __restrict__ B0, const signed char* __restrict__ B1,
    const float* __restrict__ bias0, const float* __restrict__ bias1,
    const float* __restrict__ Wfc, const float* __restrict__ bfc,
    float* __restrict__ out)
{
    __shared__ __align__(16) signed char Ah0[2][16 * 144];
    __shared__ __align__(16) signed char Al0[2][16 * 144];
    __shared__ __align__(16) signed char Ah1[2][16 * 272];
    __shared__ __align__(16) signed char Al1[2][16 * 272];
    __shared__ __align__(16) signed char Bres[7][16 * 1024];  // resident L1
    __shared__ int sRow[16], sLen[16], sTmax;

    const int tid = threadIdx.x;
    const int wv = tid >> 6, lane = tid & 63;

    if (tid < 16) {
        int r = rowmap[blockIdx.x * 16 + tid];
        sRow[tid] = r; sLen[tid] = lengths[r];
    }
    for (int i = tid; i < 16 * 144; i += 512) {
        Ah0[0][i] = 0; Al0[0][i] = 0; Ah0[1][i] = 0; Al0[1][i] = 0;
    }
    for (int i = tid; i < 16 * 272; i += 512) {
        Ah1[0][i] = 0; Al1[0][i] = 0; Ah1[1][i] = 0; Al1[1][i] = 0;
    }

    // ---- per-wave setup ----
    const int ct = (wv < 7) ? wv : 0, n = lane & 15, q = lane >> 4;
    const int cell = ct * 16 + n;
    const signed char* B0w = B0 + ct * 2048 + lane * 16;
    const signed char* B1w = B1 + ct * 1024 + lane * 16;

    // stage resident L1 slice (16 frags x 1 KB per wave)
    if (wv < 7) {
#pragma unroll
        for (int fr = 0; fr < 16; ++fr)
            gload16(B1w + (size_t)fr * 7168, &Bres[wv][fr * 1024]);
    }
    __syncthreads();   // (pre-1) sRow/sLen + zero-init published
    if (tid == 0) { int m = 0; for (int i = 0; i < 16; ++i) m = max(m, sLen[i]); sTmax = m; }

    // folded per-gate constants: [0]=i,[1]=f,[3]=o negated (sigmoid path);
    // [2]=g doubled (tanh path)
    float cb0[4], cb1[4];
    int   lenR[4];
    float c0[4], c1[4];
    int offA0, offA1;
    if (wv < 7) {
        cb0[0] = -bias0[0 * 112 + cell];
        cb0[1] = -bias0[1 * 112 + cell];
        cb0[2] = 2.0f * bias0[2 * 112 + cell];
        cb0[3] = -bias0[3 * 112 + cell];
        cb1[0] = -bias1[0 * 112 + cell];
        cb1[1] = -bias1[1 * 112 + cell];
        cb1[2] = 2.0f * bias1[2 * 112 + cell];
        cb1[3] = -bias1[3 * 112 + cell];
        offA0 = n * 144 + q * 16;
        offA1 = n * 272 + q * 16;
#pragma unroll
        for (int r = 0; r < 4; ++r) {
            lenR[r] = sLen[q * 4 + r];       // C row = q*4 + r
            c0[r] = 0.f; c1[r] = 0.f;
        }
    }

    // wave 7: x loader. x(0) -> A0[1]; x(1) -> A0[0].
    int xvalid[4]; size_t xg[4]; int xa[4]; float xv[4];
    if (wv == 7) {
#pragma unroll
        for (int i = 0; i < 4; ++i) {
            int e = i * 64 + lane;
            xvalid[i] = (e < 208);
            int r = xvalid[i] ? (e / 13) : 0;
            int f = xvalid[i] ? (e - 13 * r) : 0;
            xg[i] = (size_t)sRow[r] * (T_ * F_) + f;
            xa[i] = r * 144 + 100 + f;
            xv[i] = xvalid[i] ? x[xg[i]] : 0.f;   // t = 0
        }
#pragma unroll
        for (int i = 0; i < 4; ++i) if (xvalid[i]) {
            signed char hi, lo; qsplit(xv[i] * 4096.0f, hi, lo);
            Ah0[1][xa[i]] = hi; Al0[1][xa[i]] = lo;
        }
    }
    __syncthreads();   // (pre-2) sTmax + x(0) published
    const int Tmax = sTmax;

    // ---- prologue: GEMM0 for tau=0 (reads A0[1]: x(0), h0(-1)=0) ----
    if (wv < 7) {
        i32x4 HH[4], MM[4];
#pragma unroll
        for (int g = 0; g < 4; ++g) { HH[g] = (i32x4){0,0,0,0}; MM[g] = (i32x4){0,0,0,0}; }
        i32x4 bhi[2], blo[2], ahi, alo;
        bhi[0] = *(const i32x4*)(B0w);
        blo[0] = *(const i32x4*)(B0w + 1024);
#pragma unroll
        for (int ii = 0; ii < 8; ++ii) {
            const int kt = ii >> 2, g = ii & 3, cb = ii & 1, nbf = cb ^ 1;
            if (ii + 1 < 8) {
                bhi[nbf] = *(const i32x4*)(B0w + (size_t)(ii + 1) * 14336);
                blo[nbf] = *(const i32x4*)(B0w + (size_t)(ii + 1) * 14336 + 1024);
            }
            if (g == 0) {
                ahi = *(const i32x4*)&Ah0[1][offA0 + kt * 64];
                alo = *(const i32x4*)&Al0[1][offA0 + kt * 64];
            }
            HH[g] = __builtin_amdgcn_mfma_i32_16x16x64_i8(ahi, bhi[cb], HH[g], 0, 0, 0);
            MM[g] = __builtin_amdgcn_mfma_i32_16x16x64_i8(ahi, blo[cb], MM[g], 0, 0, 0);
            MM[g] = __builtin_amdgcn_mfma_i32_16x16x64_i8(alo, bhi[cb], MM[g], 0, 0, 0);
        }
#pragma unroll
        for (int r = 0; r < 4; ++r) {
            int Ti = (HH[0][r] << 8) + MM[0][r];
            int Tf = (HH[1][r] << 8) + MM[1][r];
            int Tg = (HH[2][r] << 8) + MM[2][r];
            int To = (HH[3][r] << 8) + MM[3][r];
            float si = 1.0f / (1.0f + __expf(cb0[0] + NK0 * (float)Ti));
            float sf = 1.0f / (1.0f + __expf(cb0[1] + NK0 * (float)Tf));
            float eg = __expf(cb0[2] + DK0 * (float)Tg);
            float tg = 1.0f - 2.0f / (eg + 1.0f);
            float so = 1.0f / (1.0f + __expf(cb0[3] + NK0 * (float)To));
            float cn = sf * c0[r] + si * tg;
            float hn = so * tanh_f(cn);
            if (0 < lenR[r]) {
                c0[r] = cn;
                if (cell < 100) {
                    int m = q * 4 + r;
                    signed char hi, lo; qsplit_h(hn * 16384.0f, hi, lo);
                    Ah0[0][m * 144 + cell] = hi; Al0[0][m * 144 + cell] = lo;
                    Ah1[0][m * 272 + cell] = hi; Al1[0][m * 272 + cell] = lo;
                }
            }
        }
    } else if (wv == 7) {      // x(1) -> A0[0]
        if (1 < Tmax) {
#pragma unroll
            for (int i = 0; i < 4; ++i)
                if (xvalid[i]) xv[i] = x[xg[i] + (size_t)1 * F_];
#pragma unroll
            for (int i = 0; i < 4; ++i) if (xvalid[i]) {
                signed char hi, lo; qsplit(xv[i] * 4096.0f, hi, lo);
                Ah0[0][xa[i]] = hi; Al0[0][xa[i]] = lo;
            }
        }
    }
    __syncthreads();   // (pre-3) h0(0), x(1) published; Bres drained

// ---- one fused step; P/PN are compile-time literals (unroll-2) ----
#define STEP(I, P, PN)                                                         \
    if (wv < 7) {                                                              \
        i32x4 bhi[4], blo[4];                                                  \
        _Pragma("unroll")                                                      \
        for (int s = 0; s < 4; ++s) {                                          \
            bhi[s] = *(const i32x4*)(B0w + (size_t)s * 14336);                 \
            blo[s] = *(const i32x4*)(B0w + (size_t)s * 14336 + 1024);          \
        }                                                                      \
        i32x4 H1[4], M1[4];                                                    \
        _Pragma("unroll")                                                      \
        for (int g = 0; g < 4; ++g) { H1[g] = (i32x4){0,0,0,0}; M1[g] = (i32x4){0,0,0,0}; } \
        _Pragma("unroll")                                                      \
        for (int kt = 0; kt < 4; ++kt) {                                       \
            i32x4 a1h = *(const i32x4*)&Ah1[P][offA1 + kt * 64];               \
            i32x4 a1l = *(const i32x4*)&Al1[P][offA1 + kt * 64];               \
            _Pragma("unroll")                                                  \
            for (int g = 0; g < 4; ++g) {                                      \
                i32x4 b = *(const i32x4*)&Bres[wv][(kt * 4 + g) * 1024 + lane * 16]; \
                H1[g] = __builtin_amdgcn_mfma_i32_16x16x64_i8(a1h, b, H1[g], 0, 0, 0); \
                M1[g] = __builtin_amdgcn_mfma_i32_16x16x64_i8(a1l, b, M1[g], 0, 0, 0); \
            }                                                                  \
        }                                                                      \
        _Pragma("unroll")                                                      \
        for (int r = 0; r < 4; ++r) {                                          \
            int Ti = (H1[0][r] << 8) + M1[0][r];                               \
            int Tf = (H1[1][r] << 8) + M1[1][r];                               \
            int Tg = (H1[2][r] << 8) + M1[2][r];                               \
            int To = (H1[3][r] << 8) + M1[3][r];                               \
            float si = 1.0f / (1.0f + __expf(cb1[0] + NK1 * (float)Ti));       \
            float sf = 1.0f / (1.0f + __expf(cb1[1] + NK1 * (float)Tf));       \
            float eg = __expf(cb1[2] + DK1 * (float)Tg);                       \
            float tg = 1.0f - 2.0f / (eg + 1.0f);                              \
            float so = 1.0f / (1.0f + __expf(cb1[3] + NK1 * (float)To));       \
            float cn = sf * c1[r] + si * tg;                                   \
            float hn = so * tanh_f(cn);                                        \
            const bool upd = ((I) < lenR[r]);                                  \
            c1[r] = upd ? cn : c1[r];                                          \
            if (upd && cell < 100) {                                           \
                int m = q * 4 + r;                                             \
                signed char hi, lo; qsplit_h(hn * 16384.0f, hi, lo);           \
                Ah1[PN][m * 272 + 100 + cell] = hi;                            \
                Al1[PN][m * 272 + 100 + cell] = lo;                            \
            }                                                                  \
        }                                                                      \
        i32x4 H0[4], M0[4];                                                    \
        _Pragma("unroll")                                                      \
        for (int g = 0; g < 4; ++g) { H0[g] = (i32x4){0,0,0,0}; M0[g] = (i32x4){0,0,0,0}; } \
        i32x4 a0h, a0l;                                                        \
        _Pragma("unroll")                                                      \
        for (int ii = 0; ii < 8; ++ii) {                                       \
            const int kt = ii >> 2, g = ii & 3, s = ii & 3;                    \
            if (g == 0) {                                                      \
                a0h = *(const i32x4*)&Ah0[P][offA0 + kt * 64];                 \
                a0l = *(const i32x4*)&Al0[P][offA0 + kt * 64];                 \
            }                                                                  \
            H0[g] = __builtin_amdgcn_mfma_i32_16x16x64_i8(a0h, bhi[s], H0[g], 0, 0, 0); \
            M0[g] = __builtin_amdgcn_mfma_i32_16x16x64_i8(a0h, blo[s], M0[g], 0, 0, 0); \
            M0[g] = __builtin_amdgcn_mfma_i32_16x16x64_i8(a0l, bhi[s], M0[g], 0, 0, 0); \
            if (ii + 4 < 8) {                                                  \
                bhi[s] = *(const i32x4*)(B0w + (size_t)(ii + 4) * 14336);      \
                blo[s] = *(const i32x4*)(B0w + (size_t)(ii + 4) * 14336 + 1024); \
            }                                                                  \
        }                                                                      \
        _Pragma("unroll")                                                      \
        for (int r = 0; r < 4; ++r) {                                          \
            int Ti = (H0[0][r] << 8) + M0[0][r];                               \
            int Tf = (H0[1][r] << 8) + M0[1][r];                               \
            int Tg = (H0[2][r] << 8) + M0[2][r];                               \
            int To = (H0[3][r] << 8) + M0[3][r];                               \
            float si = 1.0f / (1.0f + __expf(cb0[0] + NK0 * (float)Ti));       \
            float sf = 1.0f / (1.0f + __expf(cb0[1] + NK0 * (float)Tf));       \
            float eg = __expf(cb0[2] + DK0 * (float)Tg);                       \
            float tg = 1.0f - 2.0f / (eg + 1.0f);                              \
            float so = 1.0f / (1.0f + __expf(cb0[3] + NK0 * (float)To));       \
            float cn = sf * c0[r] + si * tg;                                   \
            float hn = so * tanh_f(cn);                                        \
            const bool upd = ((I) + 1 < lenR[r]);                              \
            c0[r] = upd ? cn : c0[r];                                          \
            if (upd && cell < 100) {                                           \
                int m = q * 4 + r;                                             \
                signed char hi, lo; qsplit_h(hn * 16384.0f, hi, lo);           \
                Ah0[PN][m * 144 + cell] = hi; Al0[PN][m * 144 + cell] = lo;    \
                Ah1[PN][m * 272 + cell] = hi; Al1[PN][m * 272 + cell] = lo;    \
            }                                                                  \
        }                                                                      \
    } else if (wv == 7) {                                                      \
        if ((I) + 2 < Tmax) {                                                  \
            _Pragma("unroll")                                                  \
            for (int k2 = 0; k2 < 4; ++k2)                                     \
                if (xvalid[k2]) xv[k2] = x[xg[k2] + (size_t)((I) + 2) * F_];   \
            _Pragma("unroll")                                                  \
            for (int k2 = 0; k2 < 4; ++k2) if (xvalid[k2]) {                   \
                signed char hi, lo; qsplit(xv[k2] * 4096.0f, hi, lo);          \
                Ah0[PN][xa[k2]] = hi; Al0[PN][xa[k2]] = lo;                    \
            }                                                                  \
        }                                                                      \
    }                                                                          \
    __syncthreads();

    // ---- main loop, unrolled x2 (parity literal in each body) ----
    int i = 0;
    for (; i + 1 < Tmax; i += 2) {
        STEP(i, 0, 1)
        STEP(i + 1, 1, 0)
    }
    if (i < Tmax) {        // odd Tmax tail: remaining index is even -> P=0
        STEP(i, 0, 1)
    }
#undef STEP

    // final: out[b] = W_fc . h1 + b_fc; h1 (int16 repr of h/2) lives in
    // buffer len&1 (last h1 write at iter len-1 targeted parity len&1)
    if (tid < 16) {
        const int par = sLen[tid] & 1;
        float s = bfc[0];
        for (int j = 0; j < 100; ++j) {
            int a = ((int)Ah1[par][tid * 272 + 100 + j]) * 256 +
                    (int)Al1[par][tid * 272 + 100 + j];
            float h = (float)a * (1.0f / 16384.0f);
            s = fmaf(Wfc[j], h, s);
        }
        out[sRow[tid]] = s;
    }
}

// ---------------- launch ----------------
extern "C" void kernel_launch(void* const* d_in, const int* in_sizes, int n_in,
                              void* d_out, int out_size, void* d_ws, size_t ws_size,
                              hipStream_t stream) {
    const float* x    = (const float*)d_in[0];
    const int*   len  = (const int*)d_in[1];
    const float* Wih0 = (const float*)d_in[2];
    const float* Whh0 = (const float*)d_in[3];
    const float* bih0 = (const float*)d_in[4];
    const float* bhh0 = (const float*)d_in[5];
    const float* Wih1 = (const float*)d_in[6];
    const float* Whh1 = (const float*)d_in[7];
    const float* bih1 = (const float*)d_in[8];
    const float* bhh1 = (const float*)d_in[9];
    const float* Wfc  = (const float*)d_in[10];
    const float* bfc  = (const float*)d_in[11];
    float* out = (float*)d_out;

    char* ws = (char*)d_ws;   // uses 249,856 bytes
    int*         hist   = (int*)(ws + O_HIST);
    int*         rowmap = (int*)(ws + O_ROWMAP);
    float*       bias0  = (float*)(ws + O_BIAS0);
    float*       bias1  = (float*)(ws + O_BIAS1);
    signed char* B0     = (signed char*)(ws + O_B0);
    signed char* B1     = (signed char*)(ws + O_B1);

    hipMemsetAsync(hist, 0, 512, stream);
    k_hist<<<16, 256, 0, stream>>>(len, hist);
    k_scan<<<1, 64, 0, stream>>>(hist);
    k_scatter<<<16, 256, 0, stream>>>(len, hist, rowmap);
    k_prep_bias<<<2, 256, 0, stream>>>(bih0, bhh0, bih1, bhh1, bias0, bias1);
    k_prep_b_i8<<<896, 256, 0, stream>>>(Wih0, Whh0, Wih1, Whh1, B0, B1);
    k_lstm<<<256, 512, 0, stream>>>(x, len, rowmap, B0, B1, bias0, bias1, Wfc, bfc, out);
}

// Round 14
// 363.448 us; speedup vs baseline: 1.9154x; 1.4296x over previous
//
#include <hip/hip_runtime.h>
#include <math.h>

// Problem constants (B=4096, T=100, F=13, H=100)
#define B_    4096
#define T_    100
#define F_    13
#define H_    100

typedef int   i32x4 __attribute__((ext_vector_type(4)));
typedef float f32x4 __attribute__((ext_vector_type(4)));

// ---- ws layout (bytes), total 249,856 ----
#define O_HIST   0u        // 512
#define O_ROWMAP 512u      // 4096*4
#define O_BIAS0  16896u    // 448*4
#define O_BIAS1  18688u    // 448*4
#define O_B0     20480u    // L0 int16-as-2xi8: 2kt*4g*7ct*2pl*1024 = 114688
#define O_B1     135168u   // L1 int8 single plane: 4kt*4g*7ct*1024 = 114688 -> 249856

// ---- quantization scheme (v10..v13; v14 folds log2e + rcp transcendentals) --
// State (A): int16 as two i8 planes (hi*256+lo), scale 1/32768 of stored val:
//   h stored as h/2 (a = rint(h*16384)); x stored as x/8 (a = rint(x*4096)).
// L0 weights (B0): int16 = rint(w_eff*40000), i8 hi/lo planes:
//   w_eff = 2*Whh0 (h cols) or 8*Wih0 (x cols)
//   z0 = bias + KM0*(256*(Ahi.Bhi) + (Ahi.Blo + Alo.Bhi))   [Alo.Blo dropped]
// L1 weights (B1): int8 single plane w_int = rint(w*1270), LDS-resident.
//   z1 = bias + KM1*(256*(Ahi.B) + (Alo.B))
// v14: all gate math in exp2-domain (log2e folded into constants) and all
// divisions replaced by v_rcp_f32 (~1ulp; ~2 orders below the 3e-5 state
// quantization floor). IEEE divide would expand to ~9 instrs each.
#define SB0_F   40000.0f
#define LOG2E_D 1.4426950408889634
#define NK0  ((float)(-(256.0 / (32768.0 * 40000.0)) * LOG2E_D))
#define DK0  ((float)( (512.0 / (32768.0 * 40000.0)) * LOG2E_D))
#define NK1  ((float)(-(1.0 / (1270.0 * 16384.0)) * LOG2E_D))
#define DK1  ((float)( (2.0 / (1270.0 * 16384.0)) * LOG2E_D))
#define LOG2E_F     1.4426950408889634f
#define TWO_LOG2E_F 2.8853900817779268f

#if __has_builtin(__builtin_amdgcn_rcpf)
#define RCPF(x) __builtin_amdgcn_rcpf(x)
#else
#define RCPF(x) (1.0f / (x))
#endif
#if __has_builtin(__builtin_amdgcn_exp2f)
#define EXP2F(x) __builtin_amdgcn_exp2f(x)
#else
#define EXP2F(x) exp2f(x)
#endif

// B0 fragment layout (bytes): idx = ((((kt*4+g)*7+ct)*2+plane)*64+lane)*16+j
// B1 fragment layout (bytes): idx = (((kt*4+g)*7+ct)*64+lane)*16+j
// lane's frag byte j holds W[k = kt*64 + (lane>>4)*16 + j]
//                          [col = g*112 + ct*16 + (lane&15)]

// quantize with clamp (x loader path; x can exceed range)
__device__ __forceinline__ void qsplit(float v_scaled, signed char& hi, signed char& lo) {
    int a = (int)rintf(v_scaled);
    a = a > 32639 ? 32639 : (a < -32640 ? -32640 : a);
    int l = (int)(signed char)(a & 0xFF);
    hi = (signed char)((a - l) >> 8);
    lo = (signed char)l;
}
// lean quantize for h (|h|<1 -> |a|<=16384: clamp dead; sext low byte)
__device__ __forceinline__ void qsplit_h(float v_scaled, signed char& hi, signed char& lo) {
    int a = (int)rintf(v_scaled);
    int l = (int)(signed char)(a & 0xFF);
    hi = (signed char)((a - l) >> 8);
    lo = (signed char)l;
}

// async global->LDS, 16 B per lane (v6/v9/v10-validated).
__device__ __forceinline__ void gload16(const void* g, void* l) {
    __builtin_amdgcn_global_load_lds(
        (const __attribute__((address_space(1))) void*)(unsigned long long)g,
        (__attribute__((address_space(3))) void*)(unsigned)(unsigned long long)l,
        16, 0, 0);
}

// ---------------- prep: counting sort of rows by length ----------------
__global__ void k_hist(const int* __restrict__ len, int* __restrict__ hist) {
    int b = blockIdx.x * blockDim.x + threadIdx.x;
    if (b < B_) atomicAdd(&hist[len[b]], 1);
}
__global__ void k_scan(int* __restrict__ hist) {
    if (threadIdx.x == 0 && blockIdx.x == 0) {
        int acc = 0;
        for (int l = 0; l <= 100; ++l) { int c = hist[l]; hist[l] = acc; acc += c; }
    }
}
__global__ void k_scatter(const int* __restrict__ len, int* __restrict__ hist,
                          int* __restrict__ rowmap) {
    int b = blockIdx.x * blockDim.x + threadIdx.x;
    if (b < B_) {
        int pos = atomicAdd(&hist[len[b]], 1);
        rowmap[pos] = b;
    }
}

// ---------------- prep: biases (gate-major, padded) ----------------
__global__ void k_prep_bias(const float* __restrict__ bih0, const float* __restrict__ bhh0,
                            const float* __restrict__ bih1, const float* __restrict__ bhh1,
                            float* __restrict__ bias0, float* __restrict__ bias1) {
    int idx = blockIdx.x * blockDim.x + threadIdx.x;
    if (idx < 448) {
        int g = idx / 112, cell = idx % 112;
        float v0 = 0.f, v1 = 0.f;
        if (cell < 100) {
            int row = g * 100 + cell;
            v0 = bih0[row] + bhh0[row];
            v1 = bih1[row] + bhh1[row];
        }
        bias0[idx] = v0; bias1[idx] = v1;
    }
}

// ---------------- prep: weights -> fragment planes (v10, unchanged) --------
__global__ void k_prep_b_i8(const float* __restrict__ Wih0, const float* __restrict__ Whh0,
                            const float* __restrict__ Wih1, const float* __restrict__ Whh1,
                            signed char* __restrict__ B0, signed char* __restrict__ B1) {
    int idx = blockIdx.x * blockDim.x + threadIdx.x;
    if (idx >= 229376) return;                 // 114688 (L0) + 114688 (L1)
    if (idx < 114688) {                        // ---- layer 0 (int16 2-plane) ----
        int t = idx;
        int fr    = t >> 11;                   // (kt*4+g)*7 + ct
        int rem   = t & 2047;
        int plane = rem >> 10;
        int e     = rem & 1023;
        int lane = e >> 4, j = e & 15;
        int i = fr / 7, ct = fr % 7;
        int kt = i >> 2, g = i & 3;
        int k = kt * 64 + (lane >> 4) * 16 + j;
        int cell = ct * 16 + (lane & 15);
        float w = 0.f;
        if (cell < 100) {
            int row = g * 100 + cell;
            if (k < 100)      w = 2.0f * Whh0[row * 100 + k];
            else if (k < 113) w = 8.0f * Wih0[row * 13 + (k - 100)];
        }
        int a = (int)rintf(w * SB0_F);
        a = a > 32639 ? 32639 : (a < -32640 ? -32640 : a);
        int l = ((a + 128) & 255) - 128;
        B0[idx] = plane ? (signed char)l : (signed char)((a - l) >> 8);
    } else {                                   // ---- layer 1 (int8 single) ----
        int t = idx - 114688;
        int fr = t >> 10;                      // (kt*4+g)*7 + ct
        int e  = t & 1023;
        int lane = e >> 4, j = e & 15;
        int i = fr / 7, ct = fr % 7;
        int kt = i >> 2, g = i & 3;
        int k = kt * 64 + (lane >> 4) * 16 + j;
        int cell = ct * 16 + (lane & 15);
        float w = 0.f;
        if (cell < 100) {
            int row = g * 100 + cell;
            if (k < 100)      w = Wih1[row * 100 + k];
            else if (k < 200) w = Whh1[row * 100 + (k - 100)];
        }
        int a = (int)rintf(w * 1270.0f);
        a = a > 127 ? 127 : (a < -127 ? -127 : a);
        B1[t] = (signed char)a;
    }
}

// ---------------- main persistent MFMA LSTM ----------------
// v14 (resubmit after infra failure; kernel untested last round):
// v13 structure + transcendental diet (busy-CU VALU ~65%):
//  * ALL fp32 divides -> v_rcp_f32 (IEEE divide expands to ~9 instrs; rcp is
//    1 instr at ~1ulp). 5 divides/element * 8 elements/thread-step removed.
//  * exp in exp2-domain: log2e folded into gate constants (NK/DK/cb) ->
//    v_exp_f32 consumes the fma result directly (kills __expf's inner mul).
//  * tanh(cn): e2 = exp2(cn*2log2e); hn = so*(1 - 2*rcp(e2+1)).
// Everything else identical to v13 (unroll-2 parity, int-merge, lean qsplit).
// Waves 0..6: cell-tile ct, all 4 gates. Wave 7: x loader.
__global__ __attribute__((amdgpu_flat_work_group_size(512, 512), amdgpu_waves_per_eu(2, 2)))
void k_lstm(
    const float* __restrict__ x, const int* __restrict__ lengths,
    const int* __restrict__ rowmap,
    const signed char* __restrict__ B0, const signed char* __restrict__ B1,
    const float* __restrict__ bias0, const float* __restrict__ bias1,
    const float* __restrict__ Wfc, const float* __restrict__ bfc,
    float* __restrict__ out)
{
    __shared__ __align__(16) signed char Ah0[2][16 * 144];
    __shared__ __align__(16) signed char Al0[2][16 * 144];
    __shared__ __align__(16) signed char Ah1[2][16 * 272];
    __shared__ __align__(16) signed char Al1[2][16 * 272];
    __shared__ __align__(16) signed char Bres[7][16 * 1024];  // resident L1
    __shared__ int sRow[16], sLen[16], sTmax;

    const int tid = threadIdx.x;
    const int wv = tid >> 6, lane = tid & 63;

    if (tid < 16) {
        int r = rowmap[blockIdx.x * 16 + tid];
        sRow[tid] = r; sLen[tid] = lengths[r];
    }
    for (int i = tid; i < 16 * 144; i += 512) {
        Ah0[0][i] = 0; Al0[0][i] = 0; Ah0[1][i] = 0; Al0[1][i] = 0;
    }
    for (int i = tid; i < 16 * 272; i += 512) {
        Ah1[0][i] = 0; Al1[0][i] = 0; Ah1[1][i] = 0; Al1[1][i] = 0;
    }

    // ---- per-wave setup ----
    const int ct = (wv < 7) ? wv : 0, n = lane & 15, q = lane >> 4;
    const int cell = ct * 16 + n;
    const signed char* B0w = B0 + ct * 2048 + lane * 16;
    const signed char* B1w = B1 + ct * 1024 + lane * 16;

    // stage resident L1 slice (16 frags x 1 KB per wave)
    if (wv < 7) {
#pragma unroll
        for (int fr = 0; fr < 16; ++fr)
            gload16(B1w + (size_t)fr * 7168, &Bres[wv][fr * 1024]);
    }
    __syncthreads();   // (pre-1) sRow/sLen + zero-init published
    if (tid == 0) { int m = 0; for (int i = 0; i < 16; ++i) m = max(m, sLen[i]); sTmax = m; }

    // folded per-gate constants (log2e-scaled): [0]=i,[1]=f,[3]=o negated
    // (sigmoid path exp(-z) -> exp2(cb + NK*T)); [2]=g doubled (tanh path)
    float cb0[4], cb1[4];
    int   lenR[4];
    float c0[4], c1[4];
    int offA0, offA1;
    if (wv < 7) {
        cb0[0] = -LOG2E_F * bias0[0 * 112 + cell];
        cb0[1] = -LOG2E_F * bias0[1 * 112 + cell];
        cb0[2] =  TWO_LOG2E_F * bias0[2 * 112 + cell];
        cb0[3] = -LOG2E_F * bias0[3 * 112 + cell];
        cb1[0] = -LOG2E_F * bias1[0 * 112 + cell];
        cb1[1] = -LOG2E_F * bias1[1 * 112 + cell];
        cb1[2] =  TWO_LOG2E_F * bias1[2 * 112 + cell];
        cb1[3] = -LOG2E_F * bias1[3 * 112 + cell];
        offA0 = n * 144 + q * 16;
        offA1 = n * 272 + q * 16;
#pragma unroll
        for (int r = 0; r < 4; ++r) {
            lenR[r] = sLen[q * 4 + r];       // C row = q*4 + r
            c0[r] = 0.f; c1[r] = 0.f;
        }
    }

    // wave 7: x loader. x(0) -> A0[1]; x(1) -> A0[0].
    int xvalid[4]; size_t xg[4]; int xa[4]; float xv[4];
    if (wv == 7) {
#pragma unroll
        for (int i = 0; i < 4; ++i) {
            int e = i * 64 + lane;
            xvalid[i] = (e < 208);
            int r = xvalid[i] ? (e / 13) : 0;
            int f = xvalid[i] ? (e - 13 * r) : 0;
            xg[i] = (size_t)sRow[r] * (T_ * F_) + f;
            xa[i] = r * 144 + 100 + f;
            xv[i] = xvalid[i] ? x[xg[i]] : 0.f;   // t = 0
        }
#pragma unroll
        for (int i = 0; i < 4; ++i) if (xvalid[i]) {
            signed char hi, lo; qsplit(xv[i] * 4096.0f, hi, lo);
            Ah0[1][xa[i]] = hi; Al0[1][xa[i]] = lo;
        }
    }
    __syncthreads();   // (pre-2) sTmax + x(0) published
    const int Tmax = sTmax;

// gate-set evaluation (exp2-domain, rcp-based) -> cn, hn
#define GATES(CB, NK, DK, H, M, R, CPREV, CN, HN)                              \
    int Ti = (H[0][R] << 8) + M[0][R];                                         \
    int Tf = (H[1][R] << 8) + M[1][R];                                         \
    int Tg = (H[2][R] << 8) + M[2][R];                                         \
    int To = (H[3][R] << 8) + M[3][R];                                         \
    float si = RCPF(1.0f + EXP2F(CB[0] + NK * (float)Ti));                     \
    float sf = RCPF(1.0f + EXP2F(CB[1] + NK * (float)Tf));                     \
    float eg = EXP2F(CB[2] + DK * (float)Tg);                                  \
    float tg = 1.0f - 2.0f * RCPF(eg + 1.0f);                                  \
    float so = RCPF(1.0f + EXP2F(CB[3] + NK * (float)To));                     \
    float CN = sf * CPREV + si * tg;                                           \
    float e2_ = EXP2F(CN * TWO_LOG2E_F);                                       \
    float HN = so * (1.0f - 2.0f * RCPF(e2_ + 1.0f));

    // ---- prologue: GEMM0 for tau=0 (reads A0[1]: x(0), h0(-1)=0) ----
    if (wv < 7) {
        i32x4 HH[4], MM[4];
#pragma unroll
        for (int g = 0; g < 4; ++g) { HH[g] = (i32x4){0,0,0,0}; MM[g] = (i32x4){0,0,0,0}; }
        i32x4 bhi[2], blo[2], ahi, alo;
        bhi[0] = *(const i32x4*)(B0w);
        blo[0] = *(const i32x4*)(B0w + 1024);
#pragma unroll
        for (int ii = 0; ii < 8; ++ii) {
            const int kt = ii >> 2, g = ii & 3, cb = ii & 1, nbf = cb ^ 1;
            if (ii + 1 < 8) {
                bhi[nbf] = *(const i32x4*)(B0w + (size_t)(ii + 1) * 14336);
                blo[nbf] = *(const i32x4*)(B0w + (size_t)(ii + 1) * 14336 + 1024);
            }
            if (g == 0) {
                ahi = *(const i32x4*)&Ah0[1][offA0 + kt * 64];
                alo = *(const i32x4*)&Al0[1][offA0 + kt * 64];
            }
            HH[g] = __builtin_amdgcn_mfma_i32_16x16x64_i8(ahi, bhi[cb], HH[g], 0, 0, 0);
            MM[g] = __builtin_amdgcn_mfma_i32_16x16x64_i8(ahi, blo[cb], MM[g], 0, 0, 0);
            MM[g] = __builtin_amdgcn_mfma_i32_16x16x64_i8(alo, bhi[cb], MM[g], 0, 0, 0);
        }
#pragma unroll
        for (int r = 0; r < 4; ++r) {
            GATES(cb0, NK0, DK0, HH, MM, r, c0[r], cn, hn)
            if (0 < lenR[r]) {
                c0[r] = cn;
                if (cell < 100) {
                    int m = q * 4 + r;
                    signed char hi, lo; qsplit_h(hn * 16384.0f, hi, lo);
                    Ah0[0][m * 144 + cell] = hi; Al0[0][m * 144 + cell] = lo;
                    Ah1[0][m * 272 + cell] = hi; Al1[0][m * 272 + cell] = lo;
                }
            }
        }
    } else if (wv == 7) {      // x(1) -> A0[0]
        if (1 < Tmax) {
#pragma unroll
            for (int i = 0; i < 4; ++i)
                if (xvalid[i]) xv[i] = x[xg[i] + (size_t)1 * F_];
#pragma unroll
            for (int i = 0; i < 4; ++i) if (xvalid[i]) {
                signed char hi, lo; qsplit(xv[i] * 4096.0f, hi, lo);
                Ah0[0][xa[i]] = hi; Al0[0][xa[i]] = lo;
            }
        }
    }
    __syncthreads();   // (pre-3) h0(0), x(1) published; Bres drained

// ---- one fused step; P/PN are compile-time literals (unroll-2) ----
#define STEP(I, P, PN)                                                         \
    if (wv < 7) {                                                              \
        i32x4 bhi[4], blo[4];                                                  \
        _Pragma("unroll")                                                      \
        for (int s = 0; s < 4; ++s) {                                          \
            bhi[s] = *(const i32x4*)(B0w + (size_t)s * 14336);                 \
            blo[s] = *(const i32x4*)(B0w + (size_t)s * 14336 + 1024);          \
        }                                                                      \
        i32x4 H1[4], M1[4];                                                    \
        _Pragma("unroll")                                                      \
        for (int g = 0; g < 4; ++g) { H1[g] = (i32x4){0,0,0,0}; M1[g] = (i32x4){0,0,0,0}; } \
        _Pragma("unroll")                                                      \
        for (int kt = 0; kt < 4; ++kt) {                                       \
            i32x4 a1h = *(const i32x4*)&Ah1[P][offA1 + kt * 64];               \
            i32x4 a1l = *(const i32x4*)&Al1[P][offA1 + kt * 64];               \
            _Pragma("unroll")                                                  \
            for (int g = 0; g < 4; ++g) {                                      \
                i32x4 b = *(const i32x4*)&Bres[wv][(kt * 4 + g) * 1024 + lane * 16]; \
                H1[g] = __builtin_amdgcn_mfma_i32_16x16x64_i8(a1h, b, H1[g], 0, 0, 0); \
                M1[g] = __builtin_amdgcn_mfma_i32_16x16x64_i8(a1l, b, M1[g], 0, 0, 0); \
            }                                                                  \
        }                                                                      \
        _Pragma("unroll")                                                      \
        for (int r = 0; r < 4; ++r) {                                          \
            GATES(cb1, NK1, DK1, H1, M1, r, c1[r], cn, hn)                     \
            const bool upd = ((I) < lenR[r]);                                  \
            c1[r] = upd ? cn : c1[r];                                          \
            if (upd && cell < 100) {                                           \
                int m = q * 4 + r;                                             \
                signed char hi, lo; qsplit_h(hn * 16384.0f, hi, lo);           \
                Ah1[PN][m * 272 + 100 + cell] = hi;                            \
                Al1[PN][m * 272 + 100 + cell] = lo;                            \
            }                                                                  \
        }                                                                      \
        i32x4 H0[4], M0[4];                                                    \
        _Pragma("unroll")                                                      \
        for (int g = 0; g < 4; ++g) { H0[g] = (i32x4){0,0,0,0}; M0[g] = (i32x4){0,0,0,0}; } \
        i32x4 a0h, a0l;                                                        \
        _Pragma("unroll")                                                      \
        for (int ii = 0; ii < 8; ++ii) {                                       \
            const int kt = ii >> 2, g = ii & 3, s = ii & 3;                    \
            if (g == 0) {                                                      \
                a0h = *(const i32x4*)&Ah0[P][offA0 + kt * 64];                 \
                a0l = *(const i32x4*)&Al0[P][offA0 + kt * 64];                 \
            }                                                                  \
            H0[g] = __builtin_amdgcn_mfma_i32_16x16x64_i8(a0h, bhi[s], H0[g], 0, 0, 0); \
            M0[g] = __builtin_amdgcn_mfma_i32_16x16x64_i8(a0h, blo[s], M0[g], 0, 0, 0); \
            M0[g] = __builtin_amdgcn_mfma_i32_16x16x64_i8(a0l, bhi[s], M0[g], 0, 0, 0); \
            if (ii + 4 < 8) {                                                  \
                bhi[s] = *(const i32x4*)(B0w + (size_t)(ii + 4) * 14336);      \
                blo[s] = *(const i32x4*)(B0w + (size_t)(ii + 4) * 14336 + 1024); \
            }                                                                  \
        }                                                                      \
        _Pragma("unroll")                                                      \
        for (int r = 0; r < 4; ++r) {                                          \
            GATES(cb0, NK0, DK0, H0, M0, r, c0[r], cn, hn)                     \
            const bool upd = ((I) + 1 < lenR[r]);                              \
            c0[r] = upd ? cn : c0[r];                                          \
            if (upd && cell < 100) {                                           \
                int m = q * 4 + r;                                             \
                signed char hi, lo; qsplit_h(hn * 16384.0f, hi, lo);           \
                Ah0[PN][m * 144 + cell] = hi; Al0[PN][m * 144 + cell] = lo;    \
                Ah1[PN][m * 272 + cell] = hi; Al1[PN][m * 272 + cell] = lo;    \
            }                                                                  \
        }                                                                      \
    } else if (wv == 7) {                                                      \
        if ((I) + 2 < Tmax) {                                                  \
            _Pragma("unroll")                                                  \
            for (int k2 = 0; k2 < 4; ++k2)                                     \
                if (xvalid[k2]) xv[k2] = x[xg[k2] + (size_t)((I) + 2) * F_];   \
            _Pragma("unroll")                                                  \
            for (int k2 = 0; k2 < 4; ++k2) if (xvalid[k2]) {                   \
                signed char hi, lo; qsplit(xv[k2] * 4096.0f, hi, lo);          \
                Ah0[PN][xa[k2]] = hi; Al0[PN][xa[k2]] = lo;                    \
            }                                                                  \
        }                                                                      \
    }                                                                          \
    __syncthreads();

    // ---- main loop, unrolled x2 (parity literal in each body) ----
    int i = 0;
    for (; i + 1 < Tmax; i += 2) {
        STEP(i, 0, 1)
        STEP(i + 1, 1, 0)
    }
    if (i < Tmax) {        // odd Tmax tail: remaining index is even -> P=0
        STEP(i, 0, 1)
    }
#undef STEP
#undef GATES

    // final: out[b] = W_fc . h1 + b_fc; h1 (int16 repr of h/2) lives in
    // buffer len&1 (last h1 write at iter len-1 targeted parity len&1)
    if (tid < 16) {
        const int par = sLen[tid] & 1;
        float s = bfc[0];
        for (int j = 0; j < 100; ++j) {
            int a = ((int)Ah1[par][tid * 272 + 100 + j]) * 256 +
                    (int)Al1[par][tid * 272 + 100 + j];
            float h = (float)a * (1.0f / 16384.0f);
            s = fmaf(Wfc[j], h, s);
        }
        out[sRow[tid]] = s;
    }
}

// ---------------- launch ----------------
extern "C" void kernel_launch(void* const* d_in, const int* in_sizes, int n_in,
                              void* d_out, int out_size, void* d_ws, size_t ws_size,
                              hipStream_t stream) {
    const float* x    = (const float*)d_in[0];
    const int*   len  = (const int*)d_in[1];
    const float* Wih0 = (const float*)d_in[2];
    const float* Whh0 = (const float*)d_in[3];
    const float* bih0 = (const float*)d_in[4];
    const float* bhh0 = (const float*)d_in[5];
    const float* Wih1 = (const float*)d_in[6];
    const float* Whh1 = (const float*)d_in[7];
    const float* bih1 = (const float*)d_in[8];
    const float* bhh1 = (const float*)d_in[9];
    const float* Wfc  = (const float*)d_in[10];
    const float* bfc  = (const float*)d_in[11];
    float* out = (float*)d_out;

    char* ws = (char*)d_ws;   // uses 249,856 bytes
    int*         hist   = (int*)(ws + O_HIST);
    int*         rowmap = (int*)(ws + O_ROWMAP);
    float*       bias0  = (float*)(ws + O_BIAS0);
    float*       bias1  = (float*)(ws + O_BIAS1);
    signed char* B0     = (signed char*)(ws + O_B0);
    signed char* B1     = (signed char*)(ws + O_B1);

    hipMemsetAsync(hist, 0, 512, stream);
    k_hist<<<16, 256, 0, stream>>>(len, hist);
    k_scan<<<1, 64, 0, stream>>>(hist);
    k_scatter<<<16, 256, 0, stream>>>(len, hist, rowmap);
    k_prep_bias<<<2, 256, 0, stream>>>(bih0, bhh0, bih1, bhh1, bias0, bias1);
    k_prep_b_i8<<<896, 256, 0, stream>>>(Wih0, Whh0, Wih1, Whh1, B0, B1);
    k_lstm<<<256, 512, 0, stream>>>(x, len, rowmap, B0, B1, bias0, bias1, Wfc, bfc, out);
}

// Round 15
// 353.584 us; speedup vs baseline: 1.9688x; 1.0279x over previous
//
#include <hip/hip_runtime.h>
#include <math.h>

// Problem constants (B=4096, T=100, F=13, H=100)
#define B_    4096
#define T_    100
#define F_    13
#define H_    100

typedef int   i32x4 __attribute__((ext_vector_type(4)));
typedef float f32x4 __attribute__((ext_vector_type(4)));

// ---- ws layout (bytes), total 249,856 ----
#define O_HIST   0u        // 512
#define O_ROWMAP 512u      // 4096*4
#define O_BIAS0  16896u    // 448*4
#define O_BIAS1  18688u    // 448*4
#define O_B0     20480u    // L0 int16-as-2xi8: 2kt*4g*7ct*2pl*1024 = 114688
#define O_B1     135168u   // L1 int8 single plane: 4kt*4g*7ct*1024 = 114688 -> 249856

// ---- quantization scheme (v10..v14; v15 unifies the A-state array) ----
// State (A): int16 as two i8 planes (hi*256+lo), scale 1/32768 of stored val:
//   h stored as h/2 (a = rint(h*16384)); x stored as x/8 (a = rint(x*4096)).
// Unified A row (stride 304 B): [0,100) h0 | [100,113) x | [128,228) h1 |
//   rest 0. GEMM0 reads kt0-1 (bytes 0-127); GEMM1 reads kt0-3 (0-255).
// L0 weights (B0): int16 = rint(w_eff*40000), i8 hi/lo planes:
//   w_eff = 2*Whh0 (k<100) or 8*Wih0 (k in [100,113)); 0 elsewhere
//   z0 = bias + KM0*(256*(Ahi.Bhi) + (Ahi.Blo + Alo.Bhi))   [Alo.Blo dropped]
// L1 weights (B1): int8 single plane w_int = rint(w*1270), LDS-resident.
//   k<100 -> Wih1; k in [128,228) -> Whh1 (REMAPPED from [100,200): the A
//   x-region k100-112 multiplies zero weights -> integer sums exactly equal
//   the old layout's). z1 = bias + KM1*(256*(Ahi.B) + (Alo.B))
#define SB0_F   40000.0f
#define LOG2E_D 1.4426950408889634
#define NK0  ((float)(-(256.0 / (32768.0 * 40000.0)) * LOG2E_D))
#define DK0  ((float)( (512.0 / (32768.0 * 40000.0)) * LOG2E_D))
#define NK1  ((float)(-(1.0 / (1270.0 * 16384.0)) * LOG2E_D))
#define DK1  ((float)( (2.0 / (1270.0 * 16384.0)) * LOG2E_D))
#define LOG2E_F     1.4426950408889634f
#define TWO_LOG2E_F 2.8853900817779268f
#define ASTRIDE 304   // row stride (19*16): aligned b128 reads, 2-way banks

#if __has_builtin(__builtin_amdgcn_rcpf)
#define RCPF(x) __builtin_amdgcn_rcpf(x)
#else
#define RCPF(x) (1.0f / (x))
#endif
#if __has_builtin(__builtin_amdgcn_exp2f)
#define EXP2F(x) __builtin_amdgcn_exp2f(x)
#else
#define EXP2F(x) exp2f(x)
#endif

// B0 fragment layout (bytes): idx = ((((kt*4+g)*7+ct)*2+plane)*64+lane)*16+j
// B1 fragment layout (bytes): idx = (((kt*4+g)*7+ct)*64+lane)*16+j
// lane's frag byte j holds W[k = kt*64 + (lane>>4)*16 + j]
//                          [col = g*112 + ct*16 + (lane&15)]

// quantize with clamp (x loader path; x can exceed range)
__device__ __forceinline__ void qsplit(float v_scaled, signed char& hi, signed char& lo) {
    int a = (int)rintf(v_scaled);
    a = a > 32639 ? 32639 : (a < -32640 ? -32640 : a);
    int l = (int)(signed char)(a & 0xFF);
    hi = (signed char)((a - l) >> 8);
    lo = (signed char)l;
}
// lean quantize for h (|h|<1 -> |a|<=16384: clamp dead; sext low byte)
__device__ __forceinline__ void qsplit_h(float v_scaled, signed char& hi, signed char& lo) {
    int a = (int)rintf(v_scaled);
    int l = (int)(signed char)(a & 0xFF);
    hi = (signed char)((a - l) >> 8);
    lo = (signed char)l;
}

// async global->LDS, 16 B per lane (v6/v9/v10-validated).
__device__ __forceinline__ void gload16(const void* g, void* l) {
    __builtin_amdgcn_global_load_lds(
        (const __attribute__((address_space(1))) void*)(unsigned long long)g,
        (__attribute__((address_space(3))) void*)(unsigned)(unsigned long long)l,
        16, 0, 0);
}

// ---------------- prep: counting sort of rows by length ----------------
__global__ void k_hist(const int* __restrict__ len, int* __restrict__ hist) {
    int b = blockIdx.x * blockDim.x + threadIdx.x;
    if (b < B_) atomicAdd(&hist[len[b]], 1);
}
__global__ void k_scan(int* __restrict__ hist) {
    if (threadIdx.x == 0 && blockIdx.x == 0) {
        int acc = 0;
        for (int l = 0; l <= 100; ++l) { int c = hist[l]; hist[l] = acc; acc += c; }
    }
}
__global__ void k_scatter(const int* __restrict__ len, int* __restrict__ hist,
                          int* __restrict__ rowmap) {
    int b = blockIdx.x * blockDim.x + threadIdx.x;
    if (b < B_) {
        int pos = atomicAdd(&hist[len[b]], 1);
        rowmap[pos] = b;
    }
}

// ---------------- prep: biases (gate-major, padded) ----------------
__global__ void k_prep_bias(const float* __restrict__ bih0, const float* __restrict__ bhh0,
                            const float* __restrict__ bih1, const float* __restrict__ bhh1,
                            float* __restrict__ bias0, float* __restrict__ bias1) {
    int idx = blockIdx.x * blockDim.x + threadIdx.x;
    if (idx < 448) {
        int g = idx / 112, cell = idx % 112;
        float v0 = 0.f, v1 = 0.f;
        if (cell < 100) {
            int row = g * 100 + cell;
            v0 = bih0[row] + bhh0[row];
            v1 = bih1[row] + bhh1[row];
        }
        bias0[idx] = v0; bias1[idx] = v1;
    }
}

// ---------------- prep: weights -> fragment planes ----------------
__global__ void k_prep_b_i8(const float* __restrict__ Wih0, const float* __restrict__ Whh0,
                            const float* __restrict__ Wih1, const float* __restrict__ Whh1,
                            signed char* __restrict__ B0, signed char* __restrict__ B1) {
    int idx = blockIdx.x * blockDim.x + threadIdx.x;
    if (idx >= 229376) return;                 // 114688 (L0) + 114688 (L1)
    if (idx < 114688) {                        // ---- layer 0 (int16 2-plane) ----
        int t = idx;
        int fr    = t >> 11;                   // (kt*4+g)*7 + ct
        int rem   = t & 2047;
        int plane = rem >> 10;
        int e     = rem & 1023;
        int lane = e >> 4, j = e & 15;
        int i = fr / 7, ct = fr % 7;
        int kt = i >> 2, g = i & 3;
        int k = kt * 64 + (lane >> 4) * 16 + j;
        int cell = ct * 16 + (lane & 15);
        float w = 0.f;
        if (cell < 100) {
            int row = g * 100 + cell;
            if (k < 100)      w = 2.0f * Whh0[row * 100 + k];
            else if (k < 113) w = 8.0f * Wih0[row * 13 + (k - 100)];
        }
        int a = (int)rintf(w * SB0_F);
        a = a > 32639 ? 32639 : (a < -32640 ? -32640 : a);
        int l = ((a + 128) & 255) - 128;
        B0[idx] = plane ? (signed char)l : (signed char)((a - l) >> 8);
    } else {                                   // ---- layer 1 (int8, REMAPPED) ----
        int t = idx - 114688;
        int fr = t >> 10;                      // (kt*4+g)*7 + ct
        int e  = t & 1023;
        int lane = e >> 4, j = e & 15;
        int i = fr / 7, ct = fr % 7;
        int kt = i >> 2, g = i & 3;
        int k = kt * 64 + (lane >> 4) * 16 + j;
        int cell = ct * 16 + (lane & 15);
        float w = 0.f;
        if (cell < 100) {
            int row = g * 100 + cell;
            if (k < 100)              w = Wih1[row * 100 + k];          // h0n
            else if (k >= 128 && k < 228) w = Whh1[row * 100 + (k - 128)]; // h1
            // k in [100,128) and [228,256): 0 (x region / pad)
        }
        int a = (int)rintf(w * 1270.0f);
        a = a > 127 ? 127 : (a < -127 ? -127 : a);
        B1[t] = (signed char)a;
    }
}

// ---------------- main persistent MFMA LSTM ----------------
// v15: v14 numerics (bit-identical; absmax canary 0.0002441406) + UNIFIED
// A-state array:
//  * One [16][304] row per plane/buffer: h0 | x | h1 in the same K-space.
//    GEMM0 and GEMM1 share the same base address; h0n is written ONCE
//    (was twice: A0 + A1) -> 8 fewer ds_write_b8 + address math per
//    thread-step. B1's k-map relocated (h1 at k128-227) with zero weights
//    over the x region -> integer sums exactly equal the old layout.
//  * LDS 141.8 -> 134.2 KB. Stride 304 (19*16) keeps 2-way bank classes.
// Waves 0..6: cell-tile ct, all 4 gates. Wave 7: x loader.
__global__ __attribute__((amdgpu_flat_work_group_size(512, 512), amdgpu_waves_per_eu(2, 2)))
void k_lstm(
    const float* __restrict__ x, const int* __restrict__ lengths,
    const int* __restrict__ rowmap,
    const signed char* __restrict__ B0, const signed char* __restrict__ B1,
    const float* __restrict__ bias0, const float* __restrict__ bias1,
    const float* __restrict__ Wfc, const float* __restrict__ bfc,
    float* __restrict__ out)
{
    __shared__ __align__(16) signed char Ah[2][16 * ASTRIDE];
    __shared__ __align__(16) signed char Al[2][16 * ASTRIDE];
    __shared__ __align__(16) signed char Bres[7][16 * 1024];  // resident L1
    __shared__ int sRow[16], sLen[16], sTmax;

    const int tid = threadIdx.x;
    const int wv = tid >> 6, lane = tid & 63;

    if (tid < 16) {
        int r = rowmap[blockIdx.x * 16 + tid];
        sRow[tid] = r; sLen[tid] = lengths[r];
    }
    for (int i = tid; i < 16 * ASTRIDE; i += 512) {
        Ah[0][i] = 0; Al[0][i] = 0; Ah[1][i] = 0; Al[1][i] = 0;
    }

    // ---- per-wave setup ----
    const int ct = (wv < 7) ? wv : 0, n = lane & 15, q = lane >> 4;
    const int cell = ct * 16 + n;
    const bool cellOK = (cell < 100);
    const signed char* B0w = B0 + ct * 2048 + lane * 16;
    const signed char* B1w = B1 + ct * 1024 + lane * 16;

    // stage resident L1 slice (16 frags x 1 KB per wave)
    if (wv < 7) {
#pragma unroll
        for (int fr = 0; fr < 16; ++fr)
            gload16(B1w + (size_t)fr * 7168, &Bres[wv][fr * 1024]);
    }
    __syncthreads();   // (pre-1) sRow/sLen + zero-init published
    if (tid == 0) { int m = 0; for (int i = 0; i < 16; ++i) m = max(m, sLen[i]); sTmax = m; }

    // folded per-gate constants (log2e-scaled): [0]=i,[1]=f,[3]=o negated
    // (sigmoid path exp(-z) -> exp2(cb + NK*T)); [2]=g doubled (tanh path)
    float cb0[4], cb1[4];
    int   lenR[4];
    float c0[4], c1[4];
    int offA;
    int wH0[4], wH1[4];   // precomputed write offsets (h0 / h1) per row
    if (wv < 7) {
        cb0[0] = -LOG2E_F * bias0[0 * 112 + cell];
        cb0[1] = -LOG2E_F * bias0[1 * 112 + cell];
        cb0[2] =  TWO_LOG2E_F * bias0[2 * 112 + cell];
        cb0[3] = -LOG2E_F * bias0[3 * 112 + cell];
        cb1[0] = -LOG2E_F * bias1[0 * 112 + cell];
        cb1[1] = -LOG2E_F * bias1[1 * 112 + cell];
        cb1[2] =  TWO_LOG2E_F * bias1[2 * 112 + cell];
        cb1[3] = -LOG2E_F * bias1[3 * 112 + cell];
        offA = n * ASTRIDE + q * 16;
#pragma unroll
        for (int r = 0; r < 4; ++r) {
            lenR[r] = sLen[q * 4 + r];       // C row = q*4 + r
            c0[r] = 0.f; c1[r] = 0.f;
            wH0[r] = (q * 4 + r) * ASTRIDE + cell;
            wH1[r] = wH0[r] + 128;
        }
    }

    // wave 7: x loader. x(0) -> A[1]; x(1) -> A[0].
    int xvalid[4]; size_t xg[4]; int xa[4]; float xv[4];
    if (wv == 7) {
#pragma unroll
        for (int i = 0; i < 4; ++i) {
            int e = i * 64 + lane;
            xvalid[i] = (e < 208);
            int r = xvalid[i] ? (e / 13) : 0;
            int f = xvalid[i] ? (e - 13 * r) : 0;
            xg[i] = (size_t)sRow[r] * (T_ * F_) + f;
            xa[i] = r * ASTRIDE + 100 + f;
            xv[i] = xvalid[i] ? x[xg[i]] : 0.f;   // t = 0
        }
#pragma unroll
        for (int i = 0; i < 4; ++i) if (xvalid[i]) {
            signed char hi, lo; qsplit(xv[i] * 4096.0f, hi, lo);
            Ah[1][xa[i]] = hi; Al[1][xa[i]] = lo;
        }
    }
    __syncthreads();   // (pre-2) sTmax + x(0) published
    const int Tmax = sTmax;

// gate-set evaluation (exp2-domain, rcp-based) -> cn, hn
#define GATES(CB, NK, DK, H, M, R, CPREV, CN, HN)                              \
    int Ti = (H[0][R] << 8) + M[0][R];                                         \
    int Tf = (H[1][R] << 8) + M[1][R];                                         \
    int Tg = (H[2][R] << 8) + M[2][R];                                         \
    int To = (H[3][R] << 8) + M[3][R];                                         \
    float si = RCPF(1.0f + EXP2F(CB[0] + NK * (float)Ti));                     \
    float sf = RCPF(1.0f + EXP2F(CB[1] + NK * (float)Tf));                     \
    float eg = EXP2F(CB[2] + DK * (float)Tg);                                  \
    float tg = 1.0f - 2.0f * RCPF(eg + 1.0f);                                  \
    float so = RCPF(1.0f + EXP2F(CB[3] + NK * (float)To));                     \
    float CN = sf * CPREV + si * tg;                                           \
    float e2_ = EXP2F(CN * TWO_LOG2E_F);                                       \
    float HN = so * (1.0f - 2.0f * RCPF(e2_ + 1.0f));

    // ---- prologue: GEMM0 for tau=0 (reads A[1]: x(0), h0(-1)=0) ----
    if (wv < 7) {
        i32x4 HH[4], MM[4];
#pragma unroll
        for (int g = 0; g < 4; ++g) { HH[g] = (i32x4){0,0,0,0}; MM[g] = (i32x4){0,0,0,0}; }
        i32x4 bhi[2], blo[2], ahi, alo;
        bhi[0] = *(const i32x4*)(B0w);
        blo[0] = *(const i32x4*)(B0w + 1024);
#pragma unroll
        for (int ii = 0; ii < 8; ++ii) {
            const int kt = ii >> 2, g = ii & 3, cb = ii & 1, nbf = cb ^ 1;
            if (ii + 1 < 8) {
                bhi[nbf] = *(const i32x4*)(B0w + (size_t)(ii + 1) * 14336);
                blo[nbf] = *(const i32x4*)(B0w + (size_t)(ii + 1) * 14336 + 1024);
            }
            if (g == 0) {
                ahi = *(const i32x4*)&Ah[1][offA + kt * 64];
                alo = *(const i32x4*)&Al[1][offA + kt * 64];
            }
            HH[g] = __builtin_amdgcn_mfma_i32_16x16x64_i8(ahi, bhi[cb], HH[g], 0, 0, 0);
            MM[g] = __builtin_amdgcn_mfma_i32_16x16x64_i8(ahi, blo[cb], MM[g], 0, 0, 0);
            MM[g] = __builtin_amdgcn_mfma_i32_16x16x64_i8(alo, bhi[cb], MM[g], 0, 0, 0);
        }
#pragma unroll
        for (int r = 0; r < 4; ++r) {
            GATES(cb0, NK0, DK0, HH, MM, r, c0[r], cn, hn)
            if (0 < lenR[r]) {
                c0[r] = cn;
                if (cellOK) {
                    signed char hi, lo; qsplit_h(hn * 16384.0f, hi, lo);
                    Ah[0][wH0[r]] = hi; Al[0][wH0[r]] = lo;
                }
            }
        }
    } else if (wv == 7) {      // x(1) -> A[0]
        if (1 < Tmax) {
#pragma unroll
            for (int i = 0; i < 4; ++i)
                if (xvalid[i]) xv[i] = x[xg[i] + (size_t)1 * F_];
#pragma unroll
            for (int i = 0; i < 4; ++i) if (xvalid[i]) {
                signed char hi, lo; qsplit(xv[i] * 4096.0f, hi, lo);
                Ah[0][xa[i]] = hi; Al[0][xa[i]] = lo;
            }
        }
    }
    __syncthreads();   // (pre-3) h0(0), x(1) published; Bres drained

// ---- one fused step; P/PN are compile-time literals (unroll-2) ----
#define STEP(I, P, PN)                                                         \
    if (wv < 7) {                                                              \
        i32x4 bhi[4], blo[4];                                                  \
        _Pragma("unroll")                                                      \
        for (int s = 0; s < 4; ++s) {                                          \
            bhi[s] = *(const i32x4*)(B0w + (size_t)s * 14336);                 \
            blo[s] = *(const i32x4*)(B0w + (size_t)s * 14336 + 1024);          \
        }                                                                      \
        i32x4 H1[4], M1[4];                                                    \
        _Pragma("unroll")                                                      \
        for (int g = 0; g < 4; ++g) { H1[g] = (i32x4){0,0,0,0}; M1[g] = (i32x4){0,0,0,0}; } \
        _Pragma("unroll")                                                      \
        for (int kt = 0; kt < 4; ++kt) {                                       \
            i32x4 a1h = *(const i32x4*)&Ah[P][offA + kt * 64];                 \
            i32x4 a1l = *(const i32x4*)&Al[P][offA + kt * 64];                 \
            _Pragma("unroll")                                                  \
            for (int g = 0; g < 4; ++g) {                                      \
                i32x4 b = *(const i32x4*)&Bres[wv][(kt * 4 + g) * 1024 + lane * 16]; \
                H1[g] = __builtin_amdgcn_mfma_i32_16x16x64_i8(a1h, b, H1[g], 0, 0, 0); \
                M1[g] = __builtin_amdgcn_mfma_i32_16x16x64_i8(a1l, b, M1[g], 0, 0, 0); \
            }                                                                  \
        }                                                                      \
        _Pragma("unroll")                                                      \
        for (int r = 0; r < 4; ++r) {                                          \
            GATES(cb1, NK1, DK1, H1, M1, r, c1[r], cn, hn)                     \
            const bool upd = ((I) < lenR[r]);                                  \
            c1[r] = upd ? cn : c1[r];                                          \
            if (upd && cellOK) {                                               \
                signed char hi, lo; qsplit_h(hn * 16384.0f, hi, lo);           \
                Ah[PN][wH1[r]] = hi; Al[PN][wH1[r]] = lo;                      \
            }                                                                  \
        }                                                                      \
        i32x4 H0[4], M0[4];                                                    \
        _Pragma("unroll")                                                      \
        for (int g = 0; g < 4; ++g) { H0[g] = (i32x4){0,0,0,0}; M0[g] = (i32x4){0,0,0,0}; } \
        i32x4 a0h, a0l;                                                        \
        _Pragma("unroll")                                                      \
        for (int ii = 0; ii < 8; ++ii) {                                       \
            const int kt = ii >> 2, g = ii & 3, s = ii & 3;                    \
            if (g == 0) {                                                      \
                a0h = *(const i32x4*)&Ah[P][offA + kt * 64];                   \
                a0l = *(const i32x4*)&Al[P][offA + kt * 64];                   \
            }                                                                  \
            H0[g] = __builtin_amdgcn_mfma_i32_16x16x64_i8(a0h, bhi[s], H0[g], 0, 0, 0); \
            M0[g] = __builtin_amdgcn_mfma_i32_16x16x64_i8(a0h, blo[s], M0[g], 0, 0, 0); \
            M0[g] = __builtin_amdgcn_mfma_i32_16x16x64_i8(a0l, bhi[s], M0[g], 0, 0, 0); \
            if (ii + 4 < 8) {                                                  \
                bhi[s] = *(const i32x4*)(B0w + (size_t)(ii + 4) * 14336);      \
                blo[s] = *(const i32x4*)(B0w + (size_t)(ii + 4) * 14336 + 1024); \
            }                                                                  \
        }                                                                      \
        _Pragma("unroll")                                                      \
        for (int r = 0; r < 4; ++r) {                                          \
            GATES(cb0, NK0, DK0, H0, M0, r, c0[r], cn, hn)                     \
            const bool upd = ((I) + 1 < lenR[r]);                              \
            c0[r] = upd ? cn : c0[r];                                          \
            if (upd && cellOK) {                                               \
                signed char hi, lo; qsplit_h(hn * 16384.0f, hi, lo);           \
                Ah[PN][wH0[r]] = hi; Al[PN][wH0[r]] = lo;                      \
            }                                                                  \
        }                                                                      \
    } else if (wv == 7) {                                                      \
        if ((I) + 2 < Tmax) {                                                  \
            _Pragma("unroll")                                                  \
            for (int k2 = 0; k2 < 4; ++k2)                                     \
                if (xvalid[k2]) xv[k2] = x[xg[k2] + (size_t)((I) + 2) * F_];   \
            _Pragma("unroll")                                                  \
            for (int k2 = 0; k2 < 4; ++k2) if (xvalid[k2]) {                   \
                signed char hi, lo; qsplit(xv[k2] * 4096.0f, hi, lo);          \
                Ah[PN][xa[k2]] = hi; Al[PN][xa[k2]] = lo;                      \
            }                                                                  \
        }                                                                      \
    }                                                                          \
    __syncthreads();

    // ---- main loop, unrolled x2 (parity literal in each body) ----
    int i = 0;
    for (; i + 1 < Tmax; i += 2) {
        STEP(i, 0, 1)
        STEP(i + 1, 1, 0)
    }
    if (i < Tmax) {        // odd Tmax tail: remaining index is even -> P=0
        STEP(i, 0, 1)
    }
#undef STEP
#undef GATES

    // final: out[b] = W_fc . h1 + b_fc; h1 (int16 repr of h/2) lives in
    // buffer len&1, bytes [128,228) of the unified row
    if (tid < 16) {
        const int par = sLen[tid] & 1;
        float s = bfc[0];
        for (int j = 0; j < 100; ++j) {
            int a = ((int)Ah[par][tid * ASTRIDE + 128 + j]) * 256 +
                    (int)Al[par][tid * ASTRIDE + 128 + j];
            float h = (float)a * (1.0f / 16384.0f);
            s = fmaf(Wfc[j], h, s);
        }
        out[sRow[tid]] = s;
    }
}

// ---------------- launch ----------------
extern "C" void kernel_launch(void* const* d_in, const int* in_sizes, int n_in,
                              void* d_out, int out_size, void* d_ws, size_t ws_size,
                              hipStream_t stream) {
    const float* x    = (const float*)d_in[0];
    const int*   len  = (const int*)d_in[1];
    const float* Wih0 = (const float*)d_in[2];
    const float* Whh0 = (const float*)d_in[3];
    const float* bih0 = (const float*)d_in[4];
    const float* bhh0 = (const float*)d_in[5];
    const float* Wih1 = (const float*)d_in[6];
    const float* Whh1 = (const float*)d_in[7];
    const float* bih1 = (const float*)d_in[8];
    const float* bhh1 = (const float*)d_in[9];
    const float* Wfc  = (const float*)d_in[10];
    const float* bfc  = (const float*)d_in[11];
    float* out = (float*)d_out;

    char* ws = (char*)d_ws;   // uses 249,856 bytes
    int*         hist   = (int*)(ws + O_HIST);
    int*         rowmap = (int*)(ws + O_ROWMAP);
    float*       bias0  = (float*)(ws + O_BIAS0);
    float*       bias1  = (float*)(ws + O_BIAS1);
    signed char* B0     = (signed char*)(ws + O_B0);
    signed char* B1     = (signed char*)(ws + O_B1);

    hipMemsetAsync(hist, 0, 512, stream);
    k_hist<<<16, 256, 0, stream>>>(len, hist);
    k_scan<<<1, 64, 0, stream>>>(hist);
    k_scatter<<<16, 256, 0, stream>>>(len, hist, rowmap);
    k_prep_bias<<<2, 256, 0, stream>>>(bih0, bhh0, bih1, bhh1, bias0, bias1);
    k_prep_b_i8<<<896, 256, 0, stream>>>(Wih0, Whh0, Wih1, Whh1, B0, B1);
    k_lstm<<<256, 512, 0, stream>>>(x, len, rowmap, B0, B1, bias0, bias1, Wfc, bfc, out);
}